// Round 10
// baseline (390.516 us; speedup 1.0000x reference)
//
#include <hip/hip_runtime.h>
#include <hip/hip_bf16.h>
#include <cstdint>
#include <cstddef>

// ---------- types & helpers ----------
typedef __attribute__((ext_vector_type(8))) short short8;   // 8 x bf16
typedef __attribute__((ext_vector_type(4))) short short4v;  // 4 x bf16 (8B)
typedef __attribute__((ext_vector_type(4))) float f32x4;

#define DEVINL static __device__ __forceinline__

DEVINL float b2f(unsigned short u) {
    union { unsigned int i; float f; } v; v.i = ((unsigned int)u) << 16; return v.f;
}
DEVINL unsigned short f2b(float f) {
    union { float f; unsigned int i; } v; v.f = f;
    unsigned int x = v.i;
    return (unsigned short)((x + 0x7FFFu + ((x >> 16) & 1u)) >> 16);
}
// hardware cvt (compiler emits single-instr bf16 convert)
DEVINL unsigned short f2bh(float f) {
    __hip_bfloat16 h = __float2bfloat16(f);
    union { __hip_bfloat16 h; unsigned short u; } v; v.h = h; return v.u;
}
// short8 (8 bf16) -> two f32x4
DEVINL void cv8(short8 h, f32x4& lo, f32x4& hi) {
    #pragma unroll
    for (int j = 0; j < 4; ++j) {
        lo[j] = b2f((unsigned short)h[j]);
        hi[j] = b2f((unsigned short)h[j + 4]);
    }
}
// async global->LDS, 16B per lane; LDS dest is wave-uniform base + lane*16
DEVINL void stage16(const unsigned short* g, unsigned short* l) {
    __builtin_amdgcn_global_load_lds(
        (const __attribute__((address_space(1))) unsigned int*)g,
        (__attribute__((address_space(3))) unsigned int*)l,
        16, 0, 0);
}

static constexpr int Bsz = 4, Tn = 1024, Cn = 1024, Hn = 16, Nn = 64;
static constexpr int Mrows = Bsz * Tn;             // 4096
static constexpr size_t MX = (size_t)Mrows * Cn;   // 4,194,304
static constexpr int NCHUNK = 16, CL = 64;         // 16 chunks x 64 steps

// ---------- token-shift premix: f32 x -> 6 bf16 mixed buffers ----------
__global__ __launch_bounds__(256) void k_mix(
    const float* __restrict__ x,
    const float* __restrict__ mr, const float* __restrict__ mw,
    const float* __restrict__ mk, const float* __restrict__ mv,
    const float* __restrict__ ma, const float* __restrict__ mg,
    unsigned short* __restrict__ xr, unsigned short* __restrict__ xw,
    unsigned short* __restrict__ xk, unsigned short* __restrict__ xv,
    unsigned short* __restrict__ xa, unsigned short* __restrict__ xg)
{
    size_t e = ((size_t)blockIdx.x * 256 + threadIdx.x) * 8;
    if (e >= MX) return;
    int c = (int)(e & (Cn - 1));
    int t = (int)((e >> 10) & (Tn - 1));
    float xf[8], d[8];
    {
        f32x4 x0 = *(const f32x4*)(x + e);
        f32x4 x1 = *(const f32x4*)(x + e + 4);
        #pragma unroll
        for (int j = 0; j < 4; ++j) { xf[j] = x0[j]; xf[4 + j] = x1[j]; }
    }
    if (t > 0) {
        f32x4 p0 = *(const f32x4*)(x + e - Cn);
        f32x4 p1 = *(const f32x4*)(x + e - Cn + 4);
        #pragma unroll
        for (int j = 0; j < 4; ++j) { d[j] = p0[j] - xf[j]; d[4 + j] = p1[j] - xf[4 + j]; }
    } else {
        #pragma unroll
        for (int j = 0; j < 8; ++j) d[j] = -xf[j];
    }
    const float* ms[6] = { mr, mw, mk, mv, ma, mg };
    unsigned short* ds[6] = { xr, xw, xk, xv, xa, xg };
    #pragma unroll
    for (int p = 0; p < 6; ++p) {
        f32x4 m0 = *(const f32x4*)(ms[p] + c);
        f32x4 m1 = *(const f32x4*)(ms[p] + c + 4);
        short8 o;
        #pragma unroll
        for (int j = 0; j < 4; ++j) {
            o[j]     = (short)f2b(xf[j]     + d[j]     * m0[j]);
            o[4 + j] = (short)f2b(xf[4 + j] + d[4 + j] * m1[j]);
        }
        *(short8*)(ds[p] + e) = o;
    }
}

// ---------- 4 big weights f32->bf16 in one launch ----------
__global__ __launch_bounds__(256) void k_cvt4(
    const float* __restrict__ s0, const float* __restrict__ s1,
    const float* __restrict__ s2, const float* __restrict__ s3,
    unsigned short* __restrict__ d0, unsigned short* __restrict__ d1,
    unsigned short* __restrict__ d2, unsigned short* __restrict__ d3)
{
    int sel = blockIdx.y;
    const float* in = (sel == 0) ? s0 : (sel == 1) ? s1 : (sel == 2) ? s2 : s3;
    unsigned short* out = (sel == 0) ? d0 : (sel == 1) ? d1 : (sel == 2) ? d2 : d3;
    int i = (blockIdx.x * 256 + threadIdx.x) * 4;
    f32x4 v = *(const f32x4*)(in + i);
    short4v o;
    #pragma unroll
    for (int j = 0; j < 4; ++j) o[j] = (short)f2b(v[j]);
    *(short4v*)(out + i) = o;
}

// ---------- all 8 small-weight transposes (+cvt) in one launch ----------
__global__ __launch_bounds__(256) void k_prep(
    const float* __restrict__ w1, const float* __restrict__ w2,
    const float* __restrict__ a1, const float* __restrict__ a2,
    const float* __restrict__ v1, const float* __restrict__ v2,
    const float* __restrict__ g1, const float* __restrict__ g2,
    unsigned short* __restrict__ w1T, unsigned short* __restrict__ w2T,
    unsigned short* __restrict__ a1T, unsigned short* __restrict__ a2T,
    unsigned short* __restrict__ v1T, unsigned short* __restrict__ v2T,
    unsigned short* __restrict__ g1T, unsigned short* __restrict__ g2T)
{
    int idx = blockIdx.x * 256 + threadIdx.x;
    if (idx < 65536) {                       // w1 [1024][64] -> [64][1024]
        int r = idx >> 6, c = idx & 63;
        w1T[c * 1024 + r] = f2b(w1[idx]);
    } else if (idx < 131072) {               // w2 [64][1024] -> [1024][64]
        int j = idx - 65536; int r = j >> 10, c = j & 1023;
        w2T[c * 64 + r] = f2b(w2[j]);
    } else if (idx < 196608) {               // a1
        int j = idx - 131072; int r = j >> 6, c = j & 63;
        a1T[c * 1024 + r] = f2b(a1[j]);
    } else if (idx < 262144) {               // a2
        int j = idx - 196608; int r = j >> 10, c = j & 1023;
        a2T[c * 64 + r] = f2b(a2[j]);
    } else if (idx < 327680) {               // v1
        int j = idx - 262144; int r = j >> 6, c = j & 63;
        v1T[c * 1024 + r] = f2b(v1[j]);
    } else if (idx < 393216) {               // v2
        int j = idx - 327680; int r = j >> 10, c = j & 1023;
        v2T[c * 64 + r] = f2b(v2[j]);
    } else if (idx < 557056) {               // g1 [1024][160] -> [160][1024]
        int j = idx - 393216; int r = j / 160, c = j - r * 160;
        g1T[c * 1024 + r] = f2b(g1[j]);
    } else if (idx < 720896) {               // g2 [160][1024] -> [1024][160]
        int j = idx - 557056; int r = j >> 10, c = j & 1023;
        g2T[c * 160 + r] = f2b(g2[j]);
    }
}

// epi: 0=raw 1=tanh 2=sigmoid 3=bias+sigmoid 4=bias+decay
DEVINL void gemm_epi(f32x4 (&acc)[4][4], int m0, int n0, int N, int ldc,
                     float* Cf, unsigned short* Cb, const float* bias,
                     int lane, int epi, bool outf32)
{
    int r16 = lane & 15;
    #pragma unroll
    for (int mi = 0; mi < 4; ++mi)
        #pragma unroll
        for (int ni = 0; ni < 4; ++ni) {
            int col = n0 + ni * 16 + r16;
            if (col < N) {
                float bv = (epi >= 3) ? bias[col] : 0.f;
                #pragma unroll
                for (int r = 0; r < 4; ++r) {
                    int row = m0 + mi * 16 + (lane >> 4) * 4 + r;
                    float v = acc[mi][ni][r];
                    if (epi == 1) v = tanhf(v);
                    else if (epi == 2) v = 1.f / (1.f + expf(-v));
                    else if (epi == 3) { v += bv; v = 1.f / (1.f + expf(-v)); }
                    else if (epi == 4) { v += bv; v = expf(-0.60653066f / (1.f + expf(-v))); }
                    size_t o = (size_t)row * ldc + col;
                    if (outf32) Cf[o] = v; else Cb[o] = f2b(v);
                }
            }
        }
}

// ---------- LDS-staged GEMM body: 128x128 tile, BK=32, double-buffered ----------
DEVINL void gemm_lds_body(const unsigned short* __restrict__ A, int lda,
                          const unsigned short* __restrict__ Bt, int ldb,
                          float* __restrict__ Cf, unsigned short* __restrict__ Cb,
                          int ldc, const float* __restrict__ bias, int K,
                          int m0, int n0, int epi, int outf32)
{
    __shared__ unsigned short As[2][128 * 32];
    __shared__ unsigned short Bs[2][128 * 32];
    const int tid = threadIdx.x, wid = tid >> 6, lane = tid & 63;
    const int r16 = lane & 15, kg = lane >> 4;
    const int wr = (wid >> 1) * 64, wc = (wid & 1) * 64;

    const int srow = wid * 32 + (lane >> 2);
    const int scol = (lane & 3) * 8;
    const int lbase = wid * 1024 + lane * 8;
    const unsigned short* aS = A + (size_t)(m0 + srow) * lda + scol;
    const unsigned short* bS = Bt + (size_t)(n0 + srow) * ldb + scol;

    f32x4 acc[4][4];
    #pragma unroll
    for (int a = 0; a < 4; ++a)
        #pragma unroll
        for (int b = 0; b < 4; ++b) acc[a][b] = (f32x4){0.f, 0.f, 0.f, 0.f};

    const int nk = K >> 5;
    stage16(aS, &As[0][lbase]);
    stage16(aS + (size_t)16 * lda, &As[0][lbase + 512]);
    stage16(bS, &Bs[0][lbase]);
    stage16(bS + (size_t)16 * ldb, &Bs[0][lbase + 512]);
    __syncthreads();

    for (int kk = 0; kk < nk; ++kk) {
        const int buf = kk & 1;
        if (kk + 1 < nk) {
            const int k0 = (kk + 1) * 32;
            stage16(aS + k0, &As[buf ^ 1][lbase]);
            stage16(aS + k0 + (size_t)16 * lda, &As[buf ^ 1][lbase + 512]);
            stage16(bS + k0, &Bs[buf ^ 1][lbase]);
            stage16(bS + k0 + (size_t)16 * ldb, &Bs[buf ^ 1][lbase + 512]);
        }
        short8 af[4], bf[4];
        #pragma unroll
        for (int mi = 0; mi < 4; ++mi)
            af[mi] = *(const short8*)&As[buf][(wr + mi * 16 + r16) * 32 + kg * 8];
        #pragma unroll
        for (int ni = 0; ni < 4; ++ni)
            bf[ni] = *(const short8*)&Bs[buf][(wc + ni * 16 + r16) * 32 + kg * 8];
        #pragma unroll
        for (int mi = 0; mi < 4; ++mi)
            #pragma unroll
            for (int ni = 0; ni < 4; ++ni)
                acc[mi][ni] = __builtin_amdgcn_mfma_f32_16x16x32_bf16(af[mi], bf[ni], acc[mi][ni], 0, 0, 0);
        __syncthreads();
    }
    gemm_epi(acc, m0 + wr, n0 + wc, 1 << 30, ldc, Cf, Cb, bias, lane, epi, outf32 != 0);
}

// ---------- R/K/V GEMMs in one launch (grid.z selects), LDS-staged ----------
__global__ __launch_bounds__(256) void gemm_rkv(
    const unsigned short* __restrict__ A0, const unsigned short* __restrict__ A1,
    const unsigned short* __restrict__ A2,
    const unsigned short* __restrict__ B0, const unsigned short* __restrict__ B1,
    const unsigned short* __restrict__ B2,
    unsigned short* __restrict__ D0, unsigned short* __restrict__ D1,
    unsigned short* __restrict__ D2)
{
    int z = blockIdx.z;
    const unsigned short* A = (z == 0) ? A0 : (z == 1) ? A1 : A2;
    const unsigned short* Bt = (z == 0) ? B0 : (z == 1) ? B1 : B2;
    unsigned short* D = (z == 0) ? D0 : (z == 1) ? D1 : D2;
    gemm_lds_body(A, Cn, Bt, Cn, nullptr, D, Cn, nullptr, Cn,
                  blockIdx.x * 128, blockIdx.y * 128, 0, 0);
}

// ---------- the four stage-2 GEMMs in ONE launch (grid.z selects) ----------
__global__ __launch_bounds__(256) void gemm_s2(
    const unsigned short* __restrict__ hw, const unsigned short* __restrict__ ha,
    const unsigned short* __restrict__ hv, const unsigned short* __restrict__ hg,
    const unsigned short* __restrict__ w2T, const unsigned short* __restrict__ a2T,
    const unsigned short* __restrict__ v2T, const unsigned short* __restrict__ g2T,
    float* __restrict__ Wdec, unsigned short* __restrict__ Ab,
    unsigned short* __restrict__ SVb, unsigned short* __restrict__ Gb,
    const float* __restrict__ w0, const float* __restrict__ a0,
    const float* __restrict__ v0)
{
    const int z = blockIdx.z;
    const unsigned short* A  = (z == 0) ? hw : (z == 1) ? ha : (z == 2) ? hv : hg;
    const unsigned short* Bt = (z == 0) ? w2T : (z == 1) ? a2T : (z == 2) ? v2T : g2T;
    const int K = (z == 3) ? 160 : 64;
    float* Cf = (z == 0) ? Wdec : nullptr;
    unsigned short* Cb = (z == 1) ? Ab : (z == 2) ? SVb : (z == 3) ? Gb : nullptr;
    const float* bias = (z == 0) ? w0 : (z == 1) ? a0 : (z == 2) ? v0 : nullptr;
    const int epi = (z == 0) ? 4 : (z == 3) ? 0 : 3;
    gemm_lds_body(A, K, Bt, K, Cf, Cb, Cn, bias, K,
                  blockIdx.x * 128, blockIdx.y * 128, epi, z == 0);
}

// ---------- generic LDS-staged 128x128 GEMM (Wo) ----------
template<int EPI, int OUTF32>
__global__ __launch_bounds__(256) void gemm2(
    const unsigned short* __restrict__ A, int lda,
    const unsigned short* __restrict__ Bt, int ldb,
    float* __restrict__ Cf, unsigned short* __restrict__ Cb, int ldc,
    const float* __restrict__ bias, int K)
{
    gemm_lds_body(A, lda, Bt, ldb, Cf, Cb, ldc, bias, K,
                  blockIdx.x * 128, blockIdx.y * 128, EPI, OUTF32);
}

// ---------- direct-global MFMA core (kept for tall-skinny stage-1) ----------
DEVINL void gemm_core(const unsigned short* __restrict__ A, int lda,
                      const unsigned short* __restrict__ Bt, int ldb,
                      int m0, int n0, int N, int K, int r16, int k8,
                      f32x4 (&acc)[4][4])
{
    for (int k0 = 0; k0 < K; k0 += 32) {
        short8 af[4], bf[4];
        #pragma unroll
        for (int mi = 0; mi < 4; ++mi)
            af[mi] = *(const short8*)(A + (size_t)(m0 + mi * 16 + r16) * lda + k0 + k8);
        #pragma unroll
        for (int ni = 0; ni < 4; ++ni) {
            int rn = n0 + ni * 16 + r16;
            if (rn >= N) rn = N - 1;
            bf[ni] = *(const short8*)(Bt + (size_t)rn * ldb + k0 + k8);
        }
        #pragma unroll
        for (int mi = 0; mi < 4; ++mi)
            #pragma unroll
            for (int ni = 0; ni < 4; ++ni)
                acc[mi][ni] = __builtin_amdgcn_mfma_f32_16x16x32_bf16(af[mi], bf[ni], acc[mi][ni], 0, 0, 0);
    }
}

// ---------- four tall-skinny stage-1 GEMMs in one launch ----------
__global__ __launch_bounds__(256) void gemm_small1(
    const unsigned short* __restrict__ Aw, const unsigned short* __restrict__ Aa,
    const unsigned short* __restrict__ Av, const unsigned short* __restrict__ Ag,
    const unsigned short* __restrict__ Bw, const unsigned short* __restrict__ Ba,
    const unsigned short* __restrict__ Bv, const unsigned short* __restrict__ Bg,
    unsigned short* __restrict__ Dw, unsigned short* __restrict__ Da,
    unsigned short* __restrict__ Dv, unsigned short* __restrict__ Dg)
{
    int z = blockIdx.z;
    if (z < 3 && blockIdx.y > 0) return;
    const unsigned short* A = (z == 0) ? Aw : (z == 1) ? Aa : (z == 2) ? Av : Ag;
    const unsigned short* Bt = (z == 0) ? Bw : (z == 1) ? Ba : (z == 2) ? Bv : Bg;
    unsigned short* D = (z == 0) ? Dw : (z == 1) ? Da : (z == 2) ? Dv : Dg;
    const int N = (z == 3) ? 160 : 64;
    const int epi = (z == 0) ? 1 : (z == 3) ? 2 : 0;
    const int tid = threadIdx.x, wid = tid >> 6, lane = tid & 63;
    const int r16 = lane & 15, k8 = (lane >> 4) * 8;
    const int m0 = blockIdx.x * 256 + wid * 64;
    const int n0 = blockIdx.y * 64;
    f32x4 acc[4][4];
    #pragma unroll
    for (int a = 0; a < 4; ++a)
        #pragma unroll
        for (int b = 0; b < 4; ++b) acc[a][b] = (f32x4){0.f, 0.f, 0.f, 0.f};
    gemm_core(A, Cn, Bt, Cn, m0, n0, N, Cn, r16, k8, acc);
    gemm_epi(acc, m0, n0, N, N, nullptr, D, nullptr, lane, epi, false);
}

// ---------- elementwise stage 1 (bf16 buffers in place; vfirst f32) ----------
__global__ __launch_bounds__(256) void k_elem1(
    unsigned short* __restrict__ Kb, unsigned short* __restrict__ Ab,
    unsigned short* __restrict__ Vb, unsigned short* __restrict__ SVb,
    const float* __restrict__ v_first,
    const float* __restrict__ kkw, const float* __restrict__ kaw)
{
    int tid = threadIdx.x;
    size_t gh = (size_t)blockIdx.x * 4 + (tid >> 6);   // 0 .. B*T*H-1
    int lane = tid & 63;
    int h = (int)(gh & (Hn - 1));
    size_t idx = (gh >> 4) * Cn + (size_t)h * Nn + lane;
    int c = h * Nn + lane;

    float kp = b2f(Kb[idx]);
    float kkv = kp * kkw[c];
    float s = kkv * kkv;
    #pragma unroll
    for (int m = 1; m < 64; m <<= 1) s += __shfl_xor(s, m, 64);
    float kk = kkv / fmaxf(sqrtf(s), 1e-12f);

    float a = b2f(Ab[idx]);
    float kf = kp * (1.f + (a - 1.f) * kaw[c]);
    float vp = b2f(Vb[idx]), sv = b2f(SVb[idx]), vf = v_first[idx];
    float vfin = vp + (vf - vp) * sv;

    Kb[idx] = f2b(kf);
    Vb[idx] = f2b(vfin);
    SVb[idx] = f2b(-kk);
    Ab[idx] = f2b(kk * a);
}

// ================= chunked scan =================
// Phase A2 (512 thr, 32KB LDS -> 4 blocks/CU, zero tail):
//   P (prefix transfer product), Z (zero-init state), per step:
//   sa0_t -> SAp, q_t -> Qg, y0_t -> Yp, g_t -> Gg.
// w and r read from global with one-step register prefetch (L1-hot).
__global__ __launch_bounds__(512) void kA_chunk(
    const float* __restrict__ Wp, const unsigned short* __restrict__ Kp,
    const unsigned short* __restrict__ Vp, const unsigned short* __restrict__ Ap,
    const unsigned short* __restrict__ Bp, const unsigned short* __restrict__ Rp,
    float* __restrict__ Pg, float* __restrict__ Cg,
    float* __restrict__ Qg, float* __restrict__ Gg,
    float* __restrict__ Yp, float* __restrict__ SAp)
{
    __shared__ unsigned short kS[CL][64];    // 8KB each
    __shared__ unsigned short vS[CL][64];
    __shared__ unsigned short aS[CL][64];
    __shared__ unsigned short bS[CL][64];    // total 32KB -> 4 blocks/CU

    const int tid = threadIdx.x;
    const int bx = blockIdx.x;
    const int bh = bx >> 4, c = bx & 15;
    const size_t base0 = ((size_t)(bh >> 4) * Tn + (size_t)c * CL) * Cn + (size_t)(bh & 15) * Nn;

    {
        const int t = tid >> 3, seg = (tid & 7) * 8;
        const size_t g = base0 + (size_t)t * Cn + seg;
        *(short8*)&kS[t][seg] = *(const short8*)(Kp + g);
        *(short8*)&vS[t][seg] = *(const short8*)(Vp + g);
        *(short8*)&aS[t][seg] = *(const short8*)(Ap + g);
        *(short8*)&bS[t][seg] = *(const short8*)(Bp + g);
    }
    __syncthreads();

    const int o = tid & 7, i = tid >> 3;
    f32x4 P0, P1, C0, C1;
    #pragma unroll
    for (int u = 0; u < 4; ++u) {
        P0[u] = (o * 8 + u == i) ? 1.f : 0.f;
        P1[u] = (o * 8 + 4 + u == i) ? 1.f : 0.f;
    }
    C0 = (f32x4){0.f, 0.f, 0.f, 0.f};
    C1 = C0;

    const float* wp = Wp + base0 + o * 8;
    const unsigned short* rp = Rp + base0 + o * 8;
    float* ybase = Yp + base0 + i;
    float* sabase = SAp + base0 + i;
    float* qbase = Qg + (size_t)bx * 4096 + i;
    float* gbase = Gg + (size_t)bx * 4096 + i;

    short8 rnx = *(const short8*)rp;
    f32x4 w0n = *(const f32x4*)wp;
    f32x4 w1n = *(const f32x4*)(wp + 4);
    #pragma unroll 2
    for (int t = 0; t < CL; ++t) {
        short8 rc = rnx;
        f32x4 w0 = w0n, w1 = w1n;
        if (t + 1 < CL) {
            const size_t nx = (size_t)(t + 1) * Cn;
            rnx = *(const short8*)(rp + nx);
            w0n = *(const f32x4*)(wp + nx);
            w1n = *(const f32x4*)(wp + nx + 4);
        }

        f32x4 a0, a1;
        cv8(*(const short8*)&aS[t][o * 8], a0, a1);
        f32x4 dp = P0 * a0 + P1 * a1;
        f32x4 dc = C0 * a0 + C1 * a1;
        float pa = dp[0] + dp[1] + dp[2] + dp[3];
        float ca = dc[0] + dc[1] + dc[2] + dc[3];
        pa += __shfl_xor(pa, 1, 64); pa += __shfl_xor(pa, 2, 64); pa += __shfl_xor(pa, 4, 64);
        ca += __shfl_xor(ca, 1, 64); ca += __shfl_xor(ca, 2, 64); ca += __shfl_xor(ca, 4, 64);

        float vi = b2f(vS[t][i]);
        f32x4 k0, k1, b0, b1, r0, r1;
        cv8(*(const short8*)&kS[t][o * 8], k0, k1);
        cv8(*(const short8*)&bS[t][o * 8], b0, b1);
        cv8(rc, r0, r1);

        C0 = C0 * w0 + b0 * ca + k0 * vi;
        C1 = C1 * w1 + b1 * ca + k1 * vi;
        P0 = P0 * w0 + b0 * pa;
        P1 = P1 * w1 + b1 * pa;

        f32x4 yv = C0 * r0 + C1 * r1;
        f32x4 gv = P0 * r0 + P1 * r1;
        float y = yv[0] + yv[1] + yv[2] + yv[3];
        float g = gv[0] + gv[1] + gv[2] + gv[3];
        y += __shfl_xor(y, 1, 64); y += __shfl_xor(y, 2, 64); y += __shfl_xor(y, 4, 64);
        g += __shfl_xor(g, 1, 64); g += __shfl_xor(g, 2, 64); g += __shfl_xor(g, 4, 64);

        if (o == 0) {
            ybase[(size_t)t * Cn] = y;
            sabase[(size_t)t * Cn] = ca;
            qbase[t * 64] = pa;
            gbase[t * 64] = g;
        }
    }

    const size_t ob = (size_t)bx * 4096 + (size_t)i * 64 + o * 8;
    *(f32x4*)(Pg + ob)     = P0;
    *(f32x4*)(Pg + ob + 4) = P1;
    *(f32x4*)(Cg + ob)     = C0;
    *(f32x4*)(Cg + ob + 4) = C1;
}

// Phase B (MFMA): sequential chunk combine S <- S*P_c + C_c via matrix pipe.
__global__ __launch_bounds__(256, 1) void kB_combine(
    const float* __restrict__ Pg, const float* __restrict__ Cg,
    float* __restrict__ Sinit)
{
    __shared__ float Sl[64 * 65];
    __shared__ float PT[64 * 65];
    const int tid = threadIdx.x;
    const int w = tid >> 6;
    const int l = tid & 63;
    const int lr = l & 15;
    const int lg = l >> 4;
    const int bh = blockIdx.x;

    f32x4 acc[4];
    #pragma unroll
    for (int t = 0; t < 4; ++t) acc[t] = (f32x4){0.f, 0.f, 0.f, 0.f};

    f32x4 pr[4]; f32x4 cr[4];
    {
        const size_t ob = (size_t)(bh * 16) * 4096;
        #pragma unroll
        for (int u = 0; u < 4; ++u)
            pr[u] = *(const f32x4*)(Pg + ob + (size_t)tid * 16 + u * 4);
        #pragma unroll
        for (int t = 0; t < 4; ++t)
            #pragma unroll
            for (int r = 0; r < 4; ++r)
                cr[t][r] = Cg[ob + (size_t)(16 * w + 4 * lg + r) * 64 + 16 * t + lr];
    }

    for (int c = 0; c < NCHUNK; ++c) {
        const size_t ob = (size_t)(bh * 16 + c) * 4096;
        #pragma unroll
        for (int t = 0; t < 4; ++t)
            #pragma unroll
            for (int r = 0; r < 4; ++r)
                Sinit[ob + (size_t)(16 * w + 4 * lg + r) * 64 + 16 * t + lr] = acc[t][r];
        if (c == NCHUNK - 1) break;

        #pragma unroll
        for (int t = 0; t < 4; ++t)
            #pragma unroll
            for (int r = 0; r < 4; ++r)
                Sl[(16 * w + 4 * lg + r) * 65 + 16 * t + lr] = acc[t][r];
        {
            const int m = tid >> 2, j0 = (tid & 3) * 16;
            #pragma unroll
            for (int u = 0; u < 4; ++u)
                #pragma unroll
                for (int e = 0; e < 4; ++e)
                    PT[(j0 + u * 4 + e) * 65 + m] = pr[u][e];
        }
        __syncthreads();

        f32x4 prn[4] = {}, crn[4] = {};
        if (c + 1 < NCHUNK - 1) {
            const size_t obn = (size_t)(bh * 16 + c + 1) * 4096;
            #pragma unroll
            for (int u = 0; u < 4; ++u)
                prn[u] = *(const f32x4*)(Pg + obn + (size_t)tid * 16 + u * 4);
            #pragma unroll
            for (int t = 0; t < 4; ++t)
                #pragma unroll
                for (int r = 0; r < 4; ++r)
                    crn[t][r] = Cg[obn + (size_t)(16 * w + 4 * lg + r) * 64 + 16 * t + lr];
        }

        short8 ahi[2], alo[2];
        #pragma unroll
        for (int k0 = 0; k0 < 2; ++k0) {
            const float* sp = &Sl[(16 * w + lr) * 65 + k0 * 32 + lg * 8];
            #pragma unroll
            for (int j = 0; j < 8; ++j) {
                float s = sp[j];
                unsigned short h = f2bh(s);
                ahi[k0][j] = (short)h;
                alo[k0][j] = (short)f2bh(s - b2f(h));
            }
        }

        #pragma unroll
        for (int t = 0; t < 4; ++t) {
            f32x4 nacc = cr[t];
            #pragma unroll
            for (int k0 = 0; k0 < 2; ++k0) {
                short8 bhi, blo;
                const float* pp = &PT[(16 * t + lr) * 65 + k0 * 32 + lg * 8];
                #pragma unroll
                for (int j = 0; j < 8; ++j) {
                    float p = pp[j];
                    unsigned short h = f2bh(p);
                    bhi[j] = (short)h;
                    blo[j] = (short)f2bh(p - b2f(h));
                }
                nacc = __builtin_amdgcn_mfma_f32_16x16x32_bf16(ahi[k0], bhi, nacc, 0, 0, 0);
                nacc = __builtin_amdgcn_mfma_f32_16x16x32_bf16(ahi[k0], blo, nacc, 0, 0, 0);
                nacc = __builtin_amdgcn_mfma_f32_16x16x32_bf16(alo[k0], bhi, nacc, 0, 0, 0);
            }
            acc[t] = nacc;
        }
        __syncthreads();
        #pragma unroll
        for (int u = 0; u < 4; ++u) { pr[u] = prn[u]; cr[u] = crn[u]; }
    }
}

// Phase D (MFMA): exact correction per (chain, chunk>=1):
//   SA_chunk[t][i] += sum_l Q[t][l] * S0[i][l]
//   Y_chunk[t][i]  += sum_l G[t][l] * S0[i][l]
__global__ __launch_bounds__(256) void kD_corr(
    const float* __restrict__ Sinit, const float* __restrict__ Qg,
    const float* __restrict__ Gg,
    float* __restrict__ SAp, float* __restrict__ Yp)
{
    __shared__ float Ql[64 * 65];
    __shared__ float Gl[64 * 65];
    __shared__ float S0l[64 * 65];
    const int tid = threadIdx.x;
    const int bx = blockIdx.x;          // 0..959
    const int bh = bx / 15;
    const int c  = 1 + bx % 15;
    const size_t mb = (size_t)(bh * 16 + c) * 4096;
    const size_t base0 = ((size_t)(bh >> 4) * Tn + (size_t)c * CL) * Cn + (size_t)(bh & 15) * Nn;

    {
        const int r = tid >> 2, c4 = (tid & 3) * 16;
        #pragma unroll
        for (int u = 0; u < 4; ++u) {
            *(f32x4*)&Ql[r * 65 + c4 + u * 4]  = *(const f32x4*)(Qg + mb + (size_t)r * 64 + c4 + u * 4);
            *(f32x4*)&Gl[r * 65 + c4 + u * 4]  = *(const f32x4*)(Gg + mb + (size_t)r * 64 + c4 + u * 4);
            *(f32x4*)&S0l[r * 65 + c4 + u * 4] = *(const f32x4*)(Sinit + mb + (size_t)r * 64 + c4 + u * 4);
        }
    }
    __syncthreads();

    const int w = tid >> 6, l = tid & 63, lr = l & 15, lg = l >> 4;

    short8 qhi[2], qlo[2], ghi[2], glo[2];
    #pragma unroll
    for (int k0 = 0; k0 < 2; ++k0) {
        const float* qp = &Ql[(16 * w + lr) * 65 + k0 * 32 + lg * 8];
        const float* gp = &Gl[(16 * w + lr) * 65 + k0 * 32 + lg * 8];
        #pragma unroll
        for (int j = 0; j < 8; ++j) {
            float q = qp[j];
            unsigned short h = f2bh(q);
            qhi[k0][j] = (short)h;
            qlo[k0][j] = (short)f2bh(q - b2f(h));
            float g = gp[j];
            unsigned short h2 = f2bh(g);
            ghi[k0][j] = (short)h2;
            glo[k0][j] = (short)f2bh(g - b2f(h2));
        }
    }

    #pragma unroll
    for (int tt = 0; tt < 4; ++tt) {
        f32x4 accQ = (f32x4){0.f, 0.f, 0.f, 0.f};
        f32x4 accG = (f32x4){0.f, 0.f, 0.f, 0.f};
        #pragma unroll
        for (int k0 = 0; k0 < 2; ++k0) {
            short8 bhi, blo;
            const float* sp = &S0l[(16 * tt + lr) * 65 + k0 * 32 + lg * 8];
            #pragma unroll
            for (int j = 0; j < 8; ++j) {
                float s = sp[j];
                unsigned short h = f2bh(s);
                bhi[j] = (short)h;
                blo[j] = (short)f2bh(s - b2f(h));
            }
            accQ = __builtin_amdgcn_mfma_f32_16x16x32_bf16(qhi[k0], bhi, accQ, 0, 0, 0);
            accQ = __builtin_amdgcn_mfma_f32_16x16x32_bf16(qhi[k0], blo, accQ, 0, 0, 0);
            accQ = __builtin_amdgcn_mfma_f32_16x16x32_bf16(qlo[k0], bhi, accQ, 0, 0, 0);
            accG = __builtin_amdgcn_mfma_f32_16x16x32_bf16(ghi[k0], bhi, accG, 0, 0, 0);
            accG = __builtin_amdgcn_mfma_f32_16x16x32_bf16(ghi[k0], blo, accG, 0, 0, 0);
            accG = __builtin_amdgcn_mfma_f32_16x16x32_bf16(glo[k0], bhi, accG, 0, 0, 0);
        }
        #pragma unroll
        for (int r = 0; r < 4; ++r) {
            const size_t off = base0 + (size_t)(16 * w + 4 * lg + r) * Cn + 16 * tt + lr;
            SAp[off] += accQ[r];
            Yp[off]  += accG[r];
        }
    }
}

// ---------- elementwise stage 2: groupnorm + bonus + (x_att*g) -> AG (bf16) ----------
__global__ __launch_bounds__(256) void k_elem2(
    const float* __restrict__ Yb, const unsigned short* __restrict__ Rb,
    const unsigned short* __restrict__ Kb, const unsigned short* __restrict__ Vb,
    const unsigned short* __restrict__ Gb,
    const float* __restrict__ gnw, const float* __restrict__ gnb,
    const float* __restrict__ rk,
    unsigned short* __restrict__ AG)
{
    int tid = threadIdx.x;
    size_t gh = (size_t)blockIdx.x * 4 + (tid >> 6);
    int lane = tid & 63;
    int h = (int)(gh & (Hn - 1));
    size_t idx = (gh >> 4) * Cn + (size_t)h * Nn + lane;
    int c = h * Nn + lane;

    float y = Yb[idx];
    float s1 = y, s2 = y * y;
    float p = b2f(Rb[idx]) * b2f(Kb[idx]) * rk[c];
    #pragma unroll
    for (int m = 1; m < 64; m <<= 1) {
        s1 += __shfl_xor(s1, m, 64);
        s2 += __shfl_xor(s2, m, 64);
        p  += __shfl_xor(p, m, 64);
    }
    float mean = s1 * (1.f / 64.f);
    float var = s2 * (1.f / 64.f) - mean * mean;
    float xn = (y - mean) * rsqrtf(var + 0.00064f) * gnw[c] + gnb[c];
    float xatt = xn + p * b2f(Vb[idx]);
    AG[idx] = f2b(xatt * b2f(Gb[idx]));
}

// ---------- layernorm of sa_out -> state_rep + fused v_first copy ----------
__global__ __launch_bounds__(256) void k_ln(
    const float* __restrict__ SAp,
    const float* __restrict__ lnw, const float* __restrict__ lnb,
    const float* __restrict__ vf_in, float* __restrict__ vf_out,
    float* __restrict__ outp)
{
    __shared__ float red1[4], red2[4];
    int tid = threadIdx.x;
    size_t row = blockIdx.x;
    *(f32x4*)(vf_out + row * Cn + tid * 4) = *(const f32x4*)(vf_in + row * Cn + tid * 4);

    f32x4 v = *(const f32x4*)(SAp + row * Cn + tid * 4);
    float s1 = v[0] + v[1] + v[2] + v[3];
    float s2 = v[0] * v[0] + v[1] * v[1] + v[2] * v[2] + v[3] * v[3];
    #pragma unroll
    for (int m = 1; m < 64; m <<= 1) {
        s1 += __shfl_xor(s1, m, 64);
        s2 += __shfl_xor(s2, m, 64);
    }
    if ((tid & 63) == 0) { red1[tid >> 6] = s1; red2[tid >> 6] = s2; }
    __syncthreads();
    s1 = red1[0] + red1[1] + red1[2] + red1[3];
    s2 = red2[0] + red2[1] + red2[2] + red2[3];
    float mean = s1 * (1.f / 1024.f);
    float var = s2 * (1.f / 1024.f) - mean * mean;
    float rs = rsqrtf(var + 1e-5f);
    f32x4 o;
    #pragma unroll
    for (int u = 0; u < 4; ++u) {
        int c = tid * 4 + u;
        o[u] = (v[u] - mean) * rs * lnw[c] + lnb[c];
    }
    *(f32x4*)(outp + row * Cn + tid * 4) = o;
}

// ---------- launcher ----------
extern "C" void kernel_launch(void* const* d_in, const int* in_sizes, int n_in,
                              void* d_out, int out_size, void* d_ws, size_t ws_size,
                              hipStream_t stream)
{
    (void)in_sizes; (void)n_in; (void)out_size; (void)ws_size;
    const float* x      = (const float*)d_in[0];
    const float* vfirst = (const float*)d_in[1];
    const float* x_r    = (const float*)d_in[2];
    const float* x_w    = (const float*)d_in[3];
    const float* x_k    = (const float*)d_in[4];
    const float* x_v    = (const float*)d_in[5];
    const float* x_a    = (const float*)d_in[6];
    const float* x_g    = (const float*)d_in[7];
    const float* w0     = (const float*)d_in[8];
    const float* w1     = (const float*)d_in[9];
    const float* w2     = (const float*)d_in[10];
    const float* a0     = (const float*)d_in[11];
    const float* a1     = (const float*)d_in[12];
    const float* a2     = (const float*)d_in[13];
    const float* v0     = (const float*)d_in[14];
    const float* v1     = (const float*)d_in[15];
    const float* v2     = (const float*)d_in[16];
    const float* g1     = (const float*)d_in[17];
    const float* g2     = (const float*)d_in[18];
    const float* k_k    = (const float*)d_in[19];
    const float* k_a    = (const float*)d_in[20];
    const float* r_k    = (const float*)d_in[21];
    const float* Wr     = (const float*)d_in[22];
    const float* Wk     = (const float*)d_in[23];
    const float* Wv     = (const float*)d_in[24];
    const float* Wo     = (const float*)d_in[25];
    const float* gn_w   = (const float*)d_in[26];
    const float* gn_b   = (const float*)d_in[27];
    const float* ln_w   = (const float*)d_in[28];
    const float* ln_b   = (const float*)d_in[29];

    char* ws = (char*)d_ws;
    size_t off = 0;
    auto alloc = [&](size_t bytes) -> void* {
        void* p = ws + off;
        off += (bytes + 255) & ~(size_t)255;
        return p;
    };
    // bf16 big buffers (8 MiB each)
    unsigned short* Rb  = (unsigned short*)alloc(MX * 2);  // raw r; reused as AG
    unsigned short* Kb  = (unsigned short*)alloc(MX * 2);
    unsigned short* Vb  = (unsigned short*)alloc(MX * 2);
    unsigned short* SVb = (unsigned short*)alloc(MX * 2);  // v-gate sigmoid -> aa
    unsigned short* Ab  = (unsigned short*)alloc(MX * 2);  // a sigmoid -> bb
    unsigned short* Gb  = (unsigned short*)alloc(MX * 2);  // g
    float* Wdec = (float*)alloc(MX * 4);                   // decay (f32)
    float* Cg   = (float*)alloc(MX * 4);                   // chunk offsets Z
    float* Pg   = (float*)alloc(MX * 4);                   // chunk transfer mats
    float* Qg   = (float*)alloc(MX * 4);                   // q_t vectors
    float* Gg   = (float*)alloc(MX * 4);                   // g_t vectors
    // small intermediates (bf16)
    unsigned short* hw = (unsigned short*)alloc((size_t)Mrows * 64 * 2);
    unsigned short* ha = (unsigned short*)alloc((size_t)Mrows * 64 * 2);
    unsigned short* hv = (unsigned short*)alloc((size_t)Mrows * 64 * 2);
    unsigned short* hg = (unsigned short*)alloc((size_t)Mrows * 160 * 2);
    // bf16 weights
    unsigned short* WrB = (unsigned short*)alloc(1048576 * 2);
    unsigned short* WkB = (unsigned short*)alloc(1048576 * 2);
    unsigned short* WvB = (unsigned short*)alloc(1048576 * 2);
    unsigned short* WoB = (unsigned short*)alloc(1048576 * 2);
    unsigned short* w1T = (unsigned short*)alloc(65536 * 2);
    unsigned short* w2T = (unsigned short*)alloc(65536 * 2);
    unsigned short* a1T = (unsigned short*)alloc(65536 * 2);
    unsigned short* a2T = (unsigned short*)alloc(65536 * 2);
    unsigned short* v1T = (unsigned short*)alloc(65536 * 2);
    unsigned short* v2T = (unsigned short*)alloc(65536 * 2);
    unsigned short* g1T = (unsigned short*)alloc(163840 * 2);
    unsigned short* g2T = (unsigned short*)alloc(163840 * 2);
    // ~140 MiB total

    // premix buffers alias later-written regions (dead before those writes):
    unsigned short* xrB = (unsigned short*)Cg;             // dead before kA writes Cg
    unsigned short* xkB = (unsigned short*)Cg + MX;
    unsigned short* xvB = (unsigned short*)Wdec;           // dead before gemm_s2-Wdec
    unsigned short* xgB = (unsigned short*)Wdec + MX;
    unsigned short* xwB = Ab;                              // dead before gemm_s2-Ab
    unsigned short* xaB = Gb;                              // dead before gemm_s2-Gb

    float* out_o  = (float*)d_out;
    float* out_vf = out_o + MX;
    float* out_sr = out_o + 2 * MX;
    float* Sinit = out_vf;                  // chunk-initial states (dead after kD)
    float* Yb    = out_o;                   // y0 + corrections (consumed by k_elem2)
    float* SAb   = out_sr;                  // sa0 + corrections (LN'd in place)
    unsigned short* AG = Rb;

    // prep
    k_mix<<<dim3(2048), 256, 0, stream>>>(x, x_r, x_w, x_k, x_v, x_a, x_g,
                                          xrB, xwB, xkB, xvB, xaB, xgB);
    k_cvt4<<<dim3(1024, 4), 256, 0, stream>>>(Wr, Wk, Wv, Wo, WrB, WkB, WvB, WoB);
    k_prep<<<dim3(2816), 256, 0, stream>>>(w1, w2, a1, a2, v1, v2, g1, g2,
                                           w1T, w2T, a1T, a2T, v1T, v2T, g1T, g2T);

    // stage-1 GEMMs (small first: consumes xw/xa/xv/xg before rkv writes R/K/V)
    gemm_small1<<<dim3(16, 3, 4), 256, 0, stream>>>(xwB, xaB, xvB, xgB,
                                                    w1T, a1T, v1T, g1T,
                                                    hw, ha, hv, hg);
    gemm_rkv<<<dim3(32, 8, 3), 256, 0, stream>>>(xrB, xkB, xvB, WrB, WkB, WvB,
                                                 Rb, Kb, Vb);

    // stage-2 GEMMs in one z-batched launch
    gemm_s2<<<dim3(32, 8, 4), 256, 0, stream>>>(hw, ha, hv, hg,
                                                w2T, a2T, v2T, g2T,
                                                Wdec, Ab, SVb, Gb,
                                                w0, a0, v0);

    k_elem1<<<dim3(16384), 256, 0, stream>>>(Kb, Ab, Vb, SVb, vfirst, k_k, k_a);

    // chunked scan: A2 (zero-init recurrence + outputs), B (combine), D (correct)
    kA_chunk<<<dim3(1024), 512, 0, stream>>>(Wdec, Kb, Vb, SVb, Ab, Rb,
                                             Pg, Cg, Qg, Gg, Yb, SAb);
    kB_combine<<<dim3(64), 256, 0, stream>>>(Pg, Cg, Sinit);
    kD_corr<<<dim3(960), 256, 0, stream>>>(Sinit, Qg, Gg, SAb, Yb);

    k_elem2<<<dim3(16384), 256, 0, stream>>>(Yb, Rb, Kb, Vb, Gb, gn_w, gn_b, r_k, AG);

    // real outputs (k_ln also copies v_first; Sinit in out_vf is dead after kD)
    k_ln<<<dim3(4096), 256, 0, stream>>>(SAb, ln_w, ln_b, vfirst, out_vf, out_sr);
    gemm2<0, 1><<<dim3(32, 8), 256, 0, stream>>>(AG, Cn, WoB, Cn, out_o, nullptr, Cn, nullptr, Cn);
}

// Round 11
// 356.104 us; speedup vs baseline: 1.0966x; 1.0966x over previous
//
#include <hip/hip_runtime.h>
#include <hip/hip_bf16.h>
#include <cstdint>
#include <cstddef>

// ---------- types & helpers ----------
typedef __attribute__((ext_vector_type(8))) short short8;   // 8 x bf16
typedef __attribute__((ext_vector_type(4))) short short4v;  // 4 x bf16 (8B)
typedef __attribute__((ext_vector_type(4))) float f32x4;

#define DEVINL static __device__ __forceinline__

DEVINL float b2f(unsigned short u) {
    union { unsigned int i; float f; } v; v.i = ((unsigned int)u) << 16; return v.f;
}
DEVINL unsigned short f2b(float f) {
    union { float f; unsigned int i; } v; v.f = f;
    unsigned int x = v.i;
    return (unsigned short)((x + 0x7FFFu + ((x >> 16) & 1u)) >> 16);
}
// hardware cvt (compiler emits single-instr bf16 convert)
DEVINL unsigned short f2bh(float f) {
    __hip_bfloat16 h = __float2bfloat16(f);
    union { __hip_bfloat16 h; unsigned short u; } v; v.h = h; return v.u;
}
// short8 (8 bf16) -> two f32x4
DEVINL void cv8(short8 h, f32x4& lo, f32x4& hi) {
    #pragma unroll
    for (int j = 0; j < 4; ++j) {
        lo[j] = b2f((unsigned short)h[j]);
        hi[j] = b2f((unsigned short)h[j + 4]);
    }
}
// async global->LDS, 16B per lane; LDS dest is wave-uniform base + lane*16
DEVINL void stage16(const unsigned short* g, unsigned short* l) {
    __builtin_amdgcn_global_load_lds(
        (const __attribute__((address_space(1))) unsigned int*)g,
        (__attribute__((address_space(3))) unsigned int*)l,
        16, 0, 0);
}

static constexpr int Bsz = 4, Tn = 1024, Cn = 1024, Hn = 16, Nn = 64;
static constexpr int Mrows = Bsz * Tn;             // 4096
static constexpr size_t MX = (size_t)Mrows * Cn;   // 4,194,304
static constexpr int NCHUNK = 16, CL = 64;         // 16 chunks x 64 steps

// ---------- fused prep: token-shift premix + big-weight cvt + small transposes ----------
__global__ __launch_bounds__(256) void k_prep_all(
    const float* __restrict__ x,
    const float* __restrict__ mr, const float* __restrict__ mw,
    const float* __restrict__ mk, const float* __restrict__ mv,
    const float* __restrict__ ma, const float* __restrict__ mg,
    unsigned short* __restrict__ xr, unsigned short* __restrict__ xw,
    unsigned short* __restrict__ xk, unsigned short* __restrict__ xv,
    unsigned short* __restrict__ xa, unsigned short* __restrict__ xg,
    const float* __restrict__ Wr, const float* __restrict__ Wk,
    const float* __restrict__ Wv, const float* __restrict__ Wo,
    unsigned short* __restrict__ WrB, unsigned short* __restrict__ WkB,
    unsigned short* __restrict__ WvB, unsigned short* __restrict__ WoB,
    const float* __restrict__ w1, const float* __restrict__ w2,
    const float* __restrict__ a1, const float* __restrict__ a2,
    const float* __restrict__ v1, const float* __restrict__ v2,
    const float* __restrict__ g1, const float* __restrict__ g2,
    unsigned short* __restrict__ w1T, unsigned short* __restrict__ w2T,
    unsigned short* __restrict__ a1T, unsigned short* __restrict__ a2T,
    unsigned short* __restrict__ v1T, unsigned short* __restrict__ v2T,
    unsigned short* __restrict__ g1T, unsigned short* __restrict__ g2T)
{
    const int bx = blockIdx.x;
    const int tid = threadIdx.x;
    if (bx < 2048) {
        // ---- token-shift premix ----
        size_t e = ((size_t)bx * 256 + tid) * 8;
        int c = (int)(e & (Cn - 1));
        int t = (int)((e >> 10) & (Tn - 1));
        float xf[8], d[8];
        {
            f32x4 x0 = *(const f32x4*)(x + e);
            f32x4 x1 = *(const f32x4*)(x + e + 4);
            #pragma unroll
            for (int j = 0; j < 4; ++j) { xf[j] = x0[j]; xf[4 + j] = x1[j]; }
        }
        if (t > 0) {
            f32x4 p0 = *(const f32x4*)(x + e - Cn);
            f32x4 p1 = *(const f32x4*)(x + e - Cn + 4);
            #pragma unroll
            for (int j = 0; j < 4; ++j) { d[j] = p0[j] - xf[j]; d[4 + j] = p1[j] - xf[4 + j]; }
        } else {
            #pragma unroll
            for (int j = 0; j < 8; ++j) d[j] = -xf[j];
        }
        const float* ms[6] = { mr, mw, mk, mv, ma, mg };
        unsigned short* ds[6] = { xr, xw, xk, xv, xa, xg };
        #pragma unroll
        for (int p = 0; p < 6; ++p) {
            f32x4 m0 = *(const f32x4*)(ms[p] + c);
            f32x4 m1 = *(const f32x4*)(ms[p] + c + 4);
            short8 o;
            #pragma unroll
            for (int j = 0; j < 4; ++j) {
                o[j]     = (short)f2b(xf[j]     + d[j]     * m0[j]);
                o[4 + j] = (short)f2b(xf[4 + j] + d[4 + j] * m1[j]);
            }
            *(short8*)(ds[p] + e) = o;
        }
    } else if (bx < 6144) {
        // ---- big-weight f32 -> bf16 cvt ----
        int b2 = bx - 2048;
        int sel = b2 >> 10;
        const float* in = (sel == 0) ? Wr : (sel == 1) ? Wk : (sel == 2) ? Wv : Wo;
        unsigned short* out = (sel == 0) ? WrB : (sel == 1) ? WkB : (sel == 2) ? WvB : WoB;
        int i = (((b2 & 1023) << 8) + tid) * 4;
        f32x4 v = *(const f32x4*)(in + i);
        short4v o;
        #pragma unroll
        for (int j = 0; j < 4; ++j) o[j] = (short)f2b(v[j]);
        *(short4v*)(out + i) = o;
    } else {
        // ---- small-weight transposes (+cvt) ----
        int idx = (bx - 6144) * 256 + tid;
        if (idx < 65536) {                       // w1 [1024][64] -> [64][1024]
            int r = idx >> 6, c = idx & 63;
            w1T[c * 1024 + r] = f2b(w1[idx]);
        } else if (idx < 131072) {               // w2 [64][1024] -> [1024][64]
            int j = idx - 65536; int r = j >> 10, c = j & 1023;
            w2T[c * 64 + r] = f2b(w2[j]);
        } else if (idx < 196608) {               // a1
            int j = idx - 131072; int r = j >> 6, c = j & 63;
            a1T[c * 1024 + r] = f2b(a1[j]);
        } else if (idx < 262144) {               // a2
            int j = idx - 196608; int r = j >> 10, c = j & 1023;
            a2T[c * 64 + r] = f2b(a2[j]);
        } else if (idx < 327680) {               // v1
            int j = idx - 262144; int r = j >> 6, c = j & 63;
            v1T[c * 1024 + r] = f2b(v1[j]);
        } else if (idx < 393216) {               // v2
            int j = idx - 327680; int r = j >> 10, c = j & 1023;
            v2T[c * 64 + r] = f2b(v2[j]);
        } else if (idx < 557056) {               // g1 [1024][160] -> [160][1024]
            int j = idx - 393216; int r = j / 160, c = j - r * 160;
            g1T[c * 1024 + r] = f2b(g1[j]);
        } else if (idx < 720896) {               // g2 [160][1024] -> [1024][160]
            int j = idx - 557056; int r = j >> 10, c = j & 1023;
            g2T[c * 160 + r] = f2b(g2[j]);
        }
    }
}

// epi: 0=raw 1=tanh 2=sigmoid 3=bias+sigmoid 4=bias+decay
template<int EPI, int OUTF32>
DEVINL void gemm_epi(f32x4 (&acc)[4][4], int m0, int n0, int N, int ldc,
                     float* Cf, unsigned short* Cb, const float* bias, int lane)
{
    int r16 = lane & 15;
    #pragma unroll
    for (int mi = 0; mi < 4; ++mi)
        #pragma unroll
        for (int ni = 0; ni < 4; ++ni) {
            int col = n0 + ni * 16 + r16;
            if (col < N) {
                float bv = (EPI >= 3) ? bias[col] : 0.f;
                #pragma unroll
                for (int r = 0; r < 4; ++r) {
                    int row = m0 + mi * 16 + (lane >> 4) * 4 + r;
                    float v = acc[mi][ni][r];
                    if (EPI == 1) v = tanhf(v);
                    else if (EPI == 2) v = 1.f / (1.f + expf(-v));
                    else if (EPI == 3) { v += bv; v = 1.f / (1.f + expf(-v)); }
                    else if (EPI == 4) { v += bv; v = expf(-0.60653066f / (1.f + expf(-v))); }
                    size_t o = (size_t)row * ldc + col;
                    if (OUTF32) Cf[o] = v; else Cb[o] = f2b(v);
                }
            }
        }
}

// ---------- LDS-staged GEMM body: 128x128 tile, BK=32, double-buffered ----------
template<int EPI, int OUTF32>
DEVINL void gemm_lds_body(const unsigned short* __restrict__ A, int lda,
                          const unsigned short* __restrict__ Bt, int ldb,
                          float* __restrict__ Cf, unsigned short* __restrict__ Cb,
                          int ldc, const float* __restrict__ bias, int K,
                          int m0, int n0)
{
    __shared__ unsigned short As[2][128 * 32];
    __shared__ unsigned short Bs[2][128 * 32];
    const int tid = threadIdx.x, wid = tid >> 6, lane = tid & 63;
    const int r16 = lane & 15, kg = lane >> 4;
    const int wr = (wid >> 1) * 64, wc = (wid & 1) * 64;

    const int srow = wid * 32 + (lane >> 2);
    const int scol = (lane & 3) * 8;
    const int lbase = wid * 1024 + lane * 8;
    const unsigned short* aS = A + (size_t)(m0 + srow) * lda + scol;
    const unsigned short* bS = Bt + (size_t)(n0 + srow) * ldb + scol;

    f32x4 acc[4][4];
    #pragma unroll
    for (int a = 0; a < 4; ++a)
        #pragma unroll
        for (int b = 0; b < 4; ++b) acc[a][b] = (f32x4){0.f, 0.f, 0.f, 0.f};

    const int nk = K >> 5;
    stage16(aS, &As[0][lbase]);
    stage16(aS + (size_t)16 * lda, &As[0][lbase + 512]);
    stage16(bS, &Bs[0][lbase]);
    stage16(bS + (size_t)16 * ldb, &Bs[0][lbase + 512]);
    __syncthreads();

    for (int kk = 0; kk < nk; ++kk) {
        const int buf = kk & 1;
        if (kk + 1 < nk) {
            const int k0 = (kk + 1) * 32;
            stage16(aS + k0, &As[buf ^ 1][lbase]);
            stage16(aS + k0 + (size_t)16 * lda, &As[buf ^ 1][lbase + 512]);
            stage16(bS + k0, &Bs[buf ^ 1][lbase]);
            stage16(bS + k0 + (size_t)16 * ldb, &Bs[buf ^ 1][lbase + 512]);
        }
        short8 af[4], bf[4];
        #pragma unroll
        for (int mi = 0; mi < 4; ++mi)
            af[mi] = *(const short8*)&As[buf][(wr + mi * 16 + r16) * 32 + kg * 8];
        #pragma unroll
        for (int ni = 0; ni < 4; ++ni)
            bf[ni] = *(const short8*)&Bs[buf][(wc + ni * 16 + r16) * 32 + kg * 8];
        #pragma unroll
        for (int mi = 0; mi < 4; ++mi)
            #pragma unroll
            for (int ni = 0; ni < 4; ++ni)
                acc[mi][ni] = __builtin_amdgcn_mfma_f32_16x16x32_bf16(af[mi], bf[ni], acc[mi][ni], 0, 0, 0);
        __syncthreads();
    }
    gemm_epi<EPI, OUTF32>(acc, m0 + wr, n0 + wc, 1 << 30, ldc, Cf, Cb, bias, lane);
}

// ---------- R/K/V GEMMs in one launch (grid.z selects), LDS-staged ----------
__global__ __launch_bounds__(256) void gemm_rkv(
    const unsigned short* __restrict__ A0, const unsigned short* __restrict__ A1,
    const unsigned short* __restrict__ A2,
    const unsigned short* __restrict__ B0, const unsigned short* __restrict__ B1,
    const unsigned short* __restrict__ B2,
    unsigned short* __restrict__ D0, unsigned short* __restrict__ D1,
    unsigned short* __restrict__ D2)
{
    int z = blockIdx.z;
    const unsigned short* A = (z == 0) ? A0 : (z == 1) ? A1 : A2;
    const unsigned short* Bt = (z == 0) ? B0 : (z == 1) ? B1 : B2;
    unsigned short* D = (z == 0) ? D0 : (z == 1) ? D1 : D2;
    gemm_lds_body<0, 0>(A, Cn, Bt, Cn, nullptr, D, Cn, nullptr, Cn,
                        blockIdx.x * 128, blockIdx.y * 128);
}

// ---------- the four stage-2 GEMMs in ONE launch, compile-time epilogues ----------
__global__ __launch_bounds__(256) void gemm_s2(
    const unsigned short* __restrict__ hw, const unsigned short* __restrict__ ha,
    const unsigned short* __restrict__ hv, const unsigned short* __restrict__ hg,
    const unsigned short* __restrict__ w2T, const unsigned short* __restrict__ a2T,
    const unsigned short* __restrict__ v2T, const unsigned short* __restrict__ g2T,
    float* __restrict__ Wdec, unsigned short* __restrict__ Ab,
    unsigned short* __restrict__ SVb, unsigned short* __restrict__ Gb,
    const float* __restrict__ w0, const float* __restrict__ a0,
    const float* __restrict__ v0)
{
    const int z = blockIdx.z;
    const int m0 = blockIdx.x * 128, n0 = blockIdx.y * 128;
    if (z == 0)
        gemm_lds_body<4, 1>(hw, 64, w2T, 64, Wdec, nullptr, Cn, w0, 64, m0, n0);
    else if (z == 1)
        gemm_lds_body<3, 0>(ha, 64, a2T, 64, nullptr, Ab, Cn, a0, 64, m0, n0);
    else if (z == 2)
        gemm_lds_body<3, 0>(hv, 64, v2T, 64, nullptr, SVb, Cn, v0, 64, m0, n0);
    else
        gemm_lds_body<0, 0>(hg, 160, g2T, 160, nullptr, Gb, Cn, nullptr, 160, m0, n0);
}

// ---------- generic LDS-staged 128x128 GEMM (Wo) ----------
template<int EPI, int OUTF32>
__global__ __launch_bounds__(256) void gemm2(
    const unsigned short* __restrict__ A, int lda,
    const unsigned short* __restrict__ Bt, int ldb,
    float* __restrict__ Cf, unsigned short* __restrict__ Cb, int ldc,
    const float* __restrict__ bias, int K)
{
    gemm_lds_body<EPI, OUTF32>(A, lda, Bt, ldb, Cf, Cb, ldc, bias, K,
                               blockIdx.x * 128, blockIdx.y * 128);
}

// ---------- direct-global MFMA core (kept for tall-skinny stage-1) ----------
DEVINL void gemm_core(const unsigned short* __restrict__ A, int lda,
                      const unsigned short* __restrict__ Bt, int ldb,
                      int m0, int n0, int N, int K, int r16, int k8,
                      f32x4 (&acc)[4][4])
{
    for (int k0 = 0; k0 < K; k0 += 32) {
        short8 af[4], bf[4];
        #pragma unroll
        for (int mi = 0; mi < 4; ++mi)
            af[mi] = *(const short8*)(A + (size_t)(m0 + mi * 16 + r16) * lda + k0 + k8);
        #pragma unroll
        for (int ni = 0; ni < 4; ++ni) {
            int rn = n0 + ni * 16 + r16;
            if (rn >= N) rn = N - 1;
            bf[ni] = *(const short8*)(Bt + (size_t)rn * ldb + k0 + k8);
        }
        #pragma unroll
        for (int mi = 0; mi < 4; ++mi)
            #pragma unroll
            for (int ni = 0; ni < 4; ++ni)
                acc[mi][ni] = __builtin_amdgcn_mfma_f32_16x16x32_bf16(af[mi], bf[ni], acc[mi][ni], 0, 0, 0);
    }
}

// ---------- four tall-skinny stage-1 GEMMs in one launch ----------
__global__ __launch_bounds__(256) void gemm_small1(
    const unsigned short* __restrict__ Aw, const unsigned short* __restrict__ Aa,
    const unsigned short* __restrict__ Av, const unsigned short* __restrict__ Ag,
    const unsigned short* __restrict__ Bw, const unsigned short* __restrict__ Ba,
    const unsigned short* __restrict__ Bv, const unsigned short* __restrict__ Bg,
    unsigned short* __restrict__ Dw, unsigned short* __restrict__ Da,
    unsigned short* __restrict__ Dv, unsigned short* __restrict__ Dg)
{
    int z = blockIdx.z;
    if (z < 3 && blockIdx.y > 0) return;
    const unsigned short* A = (z == 0) ? Aw : (z == 1) ? Aa : (z == 2) ? Av : Ag;
    const unsigned short* Bt = (z == 0) ? Bw : (z == 1) ? Ba : (z == 2) ? Bv : Bg;
    unsigned short* D = (z == 0) ? Dw : (z == 1) ? Da : (z == 2) ? Dv : Dg;
    const int N = (z == 3) ? 160 : 64;
    const int tid = threadIdx.x, wid = tid >> 6, lane = tid & 63;
    const int r16 = lane & 15, k8 = (lane >> 4) * 8;
    const int m0 = blockIdx.x * 256 + wid * 64;
    const int n0 = blockIdx.y * 64;
    f32x4 acc[4][4];
    #pragma unroll
    for (int a = 0; a < 4; ++a)
        #pragma unroll
        for (int b = 0; b < 4; ++b) acc[a][b] = (f32x4){0.f, 0.f, 0.f, 0.f};
    gemm_core(A, Cn, Bt, Cn, m0, n0, N, Cn, r16, k8, acc);
    if (z == 0)      gemm_epi<1, 0>(acc, m0, n0, N, 64,  nullptr, Dw, nullptr, lane);
    else if (z == 1) gemm_epi<0, 0>(acc, m0, n0, N, 64,  nullptr, Da, nullptr, lane);
    else if (z == 2) gemm_epi<0, 0>(acc, m0, n0, N, 64,  nullptr, Dv, nullptr, lane);
    else             gemm_epi<2, 0>(acc, m0, n0, N, 160, nullptr, Dg, nullptr, lane);
}

// ================= chunked scan =================
// Phase A2 (512 thr, 32KB LDS), with k_elem1 FUSED into the staging phase:
//   raw k/a/v/sv -> kk-norm, k_final, v_final, aa=-kk, bb=kk*a (in LDS);
//   k_final/v_final also written back in place for k_elem2's bonus term.
// Then the zero-init recurrence: P, Z, and per step sa0->SAp, q->Qg, y0->Yp, g->Gg.
__global__ __launch_bounds__(512) void kA_chunk(
    const float* __restrict__ Wp,
    unsigned short* __restrict__ Kp,        // raw k -> k_final (in place)
    unsigned short* __restrict__ Vp,        // raw v -> v_final (in place)
    const unsigned short* __restrict__ SVp, // sigmoid(v-gate)
    const unsigned short* __restrict__ Aap, // sigmoid(a)
    const unsigned short* __restrict__ Rp,
    const float* __restrict__ vfirst,
    const float* __restrict__ kkw, const float* __restrict__ kaw,
    float* __restrict__ Pg, float* __restrict__ Cg,
    float* __restrict__ Qg, float* __restrict__ Gg,
    float* __restrict__ Yp, float* __restrict__ SAp)
{
    __shared__ unsigned short kS[CL][64];    // 8KB each
    __shared__ unsigned short vS[CL][64];
    __shared__ unsigned short aS[CL][64];    // aa = -kk
    __shared__ unsigned short bS[CL][64];    // bb = kk*a
    // total 32KB -> 4 blocks/CU

    const int tid = threadIdx.x;
    const int bx = blockIdx.x;
    const int bh = bx >> 4, c = bx & 15;
    const size_t base0 = ((size_t)(bh >> 4) * Tn + (size_t)c * CL) * Cn + (size_t)(bh & 15) * Nn;

    {   // ---- fused staging + elementwise-1 ----
        const int t = tid >> 3, seg = (tid & 7) * 8;
        const size_t g = base0 + (size_t)t * Cn + seg;
        const int ch = (bh & 15) * Nn + seg;

        f32x4 kv0, kv1, av0, av1, vv0, vv1, sv0, sv1;
        cv8(*(const short8*)(Kp + g), kv0, kv1);
        cv8(*(const short8*)(Aap + g), av0, av1);
        cv8(*(const short8*)(Vp + g), vv0, vv1);
        cv8(*(const short8*)(SVp + g), sv0, sv1);
        f32x4 kkw0 = *(const f32x4*)(kkw + ch), kkw1 = *(const f32x4*)(kkw + ch + 4);
        f32x4 kaw0 = *(const f32x4*)(kaw + ch), kaw1 = *(const f32x4*)(kaw + ch + 4);
        f32x4 vf0  = *(const f32x4*)(vfirst + g), vf1 = *(const f32x4*)(vfirst + g + 4);

        f32x4 kkv0 = kv0 * kkw0, kkv1 = kv1 * kkw1;
        f32x4 sq = kkv0 * kkv0 + kkv1 * kkv1;
        float s = sq[0] + sq[1] + sq[2] + sq[3];
        s += __shfl_xor(s, 1, 64); s += __shfl_xor(s, 2, 64); s += __shfl_xor(s, 4, 64);
        float inv = 1.f / fmaxf(sqrtf(s), 1e-12f);

        short8 o_a, o_b, o_k, o_v;
        #pragma unroll
        for (int j = 0; j < 4; ++j) {
            float kk_lo = kkv0[j] * inv, kk_hi = kkv1[j] * inv;
            o_a[j]     = (short)f2b(-kk_lo);
            o_a[4 + j] = (short)f2b(-kk_hi);
            o_b[j]     = (short)f2b(kk_lo * av0[j]);
            o_b[4 + j] = (short)f2b(kk_hi * av1[j]);
            float kf_lo = kv0[j] * (1.f + (av0[j] - 1.f) * kaw0[j]);
            float kf_hi = kv1[j] * (1.f + (av1[j] - 1.f) * kaw1[j]);
            o_k[j]     = (short)f2b(kf_lo);
            o_k[4 + j] = (short)f2b(kf_hi);
            float vf_lo = vv0[j] + (vf0[j] - vv0[j]) * sv0[j];
            float vf_hi = vv1[j] + (vf1[j] - vv1[j]) * sv1[j];
            o_v[j]     = (short)f2b(vf_lo);
            o_v[4 + j] = (short)f2b(vf_hi);
        }
        *(short8*)&aS[t][seg] = o_a;
        *(short8*)&bS[t][seg] = o_b;
        *(short8*)&kS[t][seg] = o_k;
        *(short8*)&vS[t][seg] = o_v;
        *(short8*)(Kp + g) = o_k;   // k_final back for k_elem2
        *(short8*)(Vp + g) = o_v;   // v_final back for k_elem2
    }
    __syncthreads();

    const int o = tid & 7, i = tid >> 3;
    f32x4 P0, P1, C0, C1;
    #pragma unroll
    for (int u = 0; u < 4; ++u) {
        P0[u] = (o * 8 + u == i) ? 1.f : 0.f;
        P1[u] = (o * 8 + 4 + u == i) ? 1.f : 0.f;
    }
    C0 = (f32x4){0.f, 0.f, 0.f, 0.f};
    C1 = C0;

    const float* wp = Wp + base0 + o * 8;
    const unsigned short* rp = Rp + base0 + o * 8;
    float* ybase = Yp + base0 + i;
    float* sabase = SAp + base0 + i;
    float* qbase = Qg + (size_t)bx * 4096 + i;
    float* gbase = Gg + (size_t)bx * 4096 + i;

    short8 rnx = *(const short8*)rp;
    f32x4 w0n = *(const f32x4*)wp;
    f32x4 w1n = *(const f32x4*)(wp + 4);
    #pragma unroll 2
    for (int t = 0; t < CL; ++t) {
        short8 rc = rnx;
        f32x4 w0 = w0n, w1 = w1n;
        if (t + 1 < CL) {
            const size_t nx = (size_t)(t + 1) * Cn;
            rnx = *(const short8*)(rp + nx);
            w0n = *(const f32x4*)(wp + nx);
            w1n = *(const f32x4*)(wp + nx + 4);
        }

        f32x4 a0, a1;
        cv8(*(const short8*)&aS[t][o * 8], a0, a1);
        f32x4 dp = P0 * a0 + P1 * a1;
        f32x4 dc = C0 * a0 + C1 * a1;
        float pa = dp[0] + dp[1] + dp[2] + dp[3];
        float ca = dc[0] + dc[1] + dc[2] + dc[3];
        pa += __shfl_xor(pa, 1, 64); pa += __shfl_xor(pa, 2, 64); pa += __shfl_xor(pa, 4, 64);
        ca += __shfl_xor(ca, 1, 64); ca += __shfl_xor(ca, 2, 64); ca += __shfl_xor(ca, 4, 64);

        float vi = b2f(vS[t][i]);
        f32x4 k0, k1, b0, b1, r0, r1;
        cv8(*(const short8*)&kS[t][o * 8], k0, k1);
        cv8(*(const short8*)&bS[t][o * 8], b0, b1);
        cv8(rc, r0, r1);

        C0 = C0 * w0 + b0 * ca + k0 * vi;
        C1 = C1 * w1 + b1 * ca + k1 * vi;
        P0 = P0 * w0 + b0 * pa;
        P1 = P1 * w1 + b1 * pa;

        f32x4 yv = C0 * r0 + C1 * r1;
        f32x4 gv = P0 * r0 + P1 * r1;
        float y = yv[0] + yv[1] + yv[2] + yv[3];
        float g = gv[0] + gv[1] + gv[2] + gv[3];
        y += __shfl_xor(y, 1, 64); y += __shfl_xor(y, 2, 64); y += __shfl_xor(y, 4, 64);
        g += __shfl_xor(g, 1, 64); g += __shfl_xor(g, 2, 64); g += __shfl_xor(g, 4, 64);

        if (o == 0) {
            ybase[(size_t)t * Cn] = y;
            sabase[(size_t)t * Cn] = ca;
            qbase[t * 64] = pa;
            gbase[t * 64] = g;
        }
    }

    const size_t ob = (size_t)bx * 4096 + (size_t)i * 64 + o * 8;
    *(f32x4*)(Pg + ob)     = P0;
    *(f32x4*)(Pg + ob + 4) = P1;
    *(f32x4*)(Cg + ob)     = C0;
    *(f32x4*)(Cg + ob + 4) = C1;
}

// Phase B (MFMA): sequential chunk combine S <- S*P_c + C_c via matrix pipe.
__global__ __launch_bounds__(256, 1) void kB_combine(
    const float* __restrict__ Pg, const float* __restrict__ Cg,
    float* __restrict__ Sinit)
{
    __shared__ float Sl[64 * 65];
    __shared__ float PT[64 * 65];
    const int tid = threadIdx.x;
    const int w = tid >> 6;
    const int l = tid & 63;
    const int lr = l & 15;
    const int lg = l >> 4;
    const int bh = blockIdx.x;

    f32x4 acc[4];
    #pragma unroll
    for (int t = 0; t < 4; ++t) acc[t] = (f32x4){0.f, 0.f, 0.f, 0.f};

    f32x4 pr[4]; f32x4 cr[4];
    {
        const size_t ob = (size_t)(bh * 16) * 4096;
        #pragma unroll
        for (int u = 0; u < 4; ++u)
            pr[u] = *(const f32x4*)(Pg + ob + (size_t)tid * 16 + u * 4);
        #pragma unroll
        for (int t = 0; t < 4; ++t)
            #pragma unroll
            for (int r = 0; r < 4; ++r)
                cr[t][r] = Cg[ob + (size_t)(16 * w + 4 * lg + r) * 64 + 16 * t + lr];
    }

    for (int c = 0; c < NCHUNK; ++c) {
        const size_t ob = (size_t)(bh * 16 + c) * 4096;
        #pragma unroll
        for (int t = 0; t < 4; ++t)
            #pragma unroll
            for (int r = 0; r < 4; ++r)
                Sinit[ob + (size_t)(16 * w + 4 * lg + r) * 64 + 16 * t + lr] = acc[t][r];
        if (c == NCHUNK - 1) break;

        #pragma unroll
        for (int t = 0; t < 4; ++t)
            #pragma unroll
            for (int r = 0; r < 4; ++r)
                Sl[(16 * w + 4 * lg + r) * 65 + 16 * t + lr] = acc[t][r];
        {
            const int m = tid >> 2, j0 = (tid & 3) * 16;
            #pragma unroll
            for (int u = 0; u < 4; ++u)
                #pragma unroll
                for (int e = 0; e < 4; ++e)
                    PT[(j0 + u * 4 + e) * 65 + m] = pr[u][e];
        }
        __syncthreads();

        f32x4 prn[4] = {}, crn[4] = {};
        if (c + 1 < NCHUNK - 1) {
            const size_t obn = (size_t)(bh * 16 + c + 1) * 4096;
            #pragma unroll
            for (int u = 0; u < 4; ++u)
                prn[u] = *(const f32x4*)(Pg + obn + (size_t)tid * 16 + u * 4);
            #pragma unroll
            for (int t = 0; t < 4; ++t)
                #pragma unroll
                for (int r = 0; r < 4; ++r)
                    crn[t][r] = Cg[obn + (size_t)(16 * w + 4 * lg + r) * 64 + 16 * t + lr];
        }

        short8 ahi[2], alo[2];
        #pragma unroll
        for (int k0 = 0; k0 < 2; ++k0) {
            const float* sp = &Sl[(16 * w + lr) * 65 + k0 * 32 + lg * 8];
            #pragma unroll
            for (int j = 0; j < 8; ++j) {
                float s = sp[j];
                unsigned short h = f2bh(s);
                ahi[k0][j] = (short)h;
                alo[k0][j] = (short)f2bh(s - b2f(h));
            }
        }

        #pragma unroll
        for (int t = 0; t < 4; ++t) {
            f32x4 nacc = cr[t];
            #pragma unroll
            for (int k0 = 0; k0 < 2; ++k0) {
                short8 bhi, blo;
                const float* pp = &PT[(16 * t + lr) * 65 + k0 * 32 + lg * 8];
                #pragma unroll
                for (int j = 0; j < 8; ++j) {
                    float p = pp[j];
                    unsigned short h = f2bh(p);
                    bhi[j] = (short)h;
                    blo[j] = (short)f2bh(p - b2f(h));
                }
                nacc = __builtin_amdgcn_mfma_f32_16x16x32_bf16(ahi[k0], bhi, nacc, 0, 0, 0);
                nacc = __builtin_amdgcn_mfma_f32_16x16x32_bf16(ahi[k0], blo, nacc, 0, 0, 0);
                nacc = __builtin_amdgcn_mfma_f32_16x16x32_bf16(alo[k0], bhi, nacc, 0, 0, 0);
            }
            acc[t] = nacc;
        }
        __syncthreads();
        #pragma unroll
        for (int u = 0; u < 4; ++u) { pr[u] = prn[u]; cr[u] = crn[u]; }
    }
}

// Phase D (MFMA): exact correction per (chain, chunk>=1):
//   SA_chunk[t][i] += sum_l Q[t][l] * S0[i][l]
//   Y_chunk[t][i]  += sum_l G[t][l] * S0[i][l]
__global__ __launch_bounds__(256) void kD_corr(
    const float* __restrict__ Sinit, const float* __restrict__ Qg,
    const float* __restrict__ Gg,
    float* __restrict__ SAp, float* __restrict__ Yp)
{
    __shared__ float Ql[64 * 65];
    __shared__ float Gl[64 * 65];
    __shared__ float S0l[64 * 65];
    const int tid = threadIdx.x;
    const int bx = blockIdx.x;          // 0..959
    const int bh = bx / 15;
    const int c  = 1 + bx % 15;
    const size_t mb = (size_t)(bh * 16 + c) * 4096;
    const size_t base0 = ((size_t)(bh >> 4) * Tn + (size_t)c * CL) * Cn + (size_t)(bh & 15) * Nn;

    {
        const int r = tid >> 2, c4 = (tid & 3) * 16;
        #pragma unroll
        for (int u = 0; u < 4; ++u) {
            *(f32x4*)&Ql[r * 65 + c4 + u * 4]  = *(const f32x4*)(Qg + mb + (size_t)r * 64 + c4 + u * 4);
            *(f32x4*)&Gl[r * 65 + c4 + u * 4]  = *(const f32x4*)(Gg + mb + (size_t)r * 64 + c4 + u * 4);
            *(f32x4*)&S0l[r * 65 + c4 + u * 4] = *(const f32x4*)(Sinit + mb + (size_t)r * 64 + c4 + u * 4);
        }
    }
    __syncthreads();

    const int w = tid >> 6, l = tid & 63, lr = l & 15, lg = l >> 4;

    short8 qhi[2], qlo[2], ghi[2], glo[2];
    #pragma unroll
    for (int k0 = 0; k0 < 2; ++k0) {
        const float* qp = &Ql[(16 * w + lr) * 65 + k0 * 32 + lg * 8];
        const float* gp = &Gl[(16 * w + lr) * 65 + k0 * 32 + lg * 8];
        #pragma unroll
        for (int j = 0; j < 8; ++j) {
            float q = qp[j];
            unsigned short h = f2bh(q);
            qhi[k0][j] = (short)h;
            qlo[k0][j] = (short)f2bh(q - b2f(h));
            float g = gp[j];
            unsigned short h2 = f2bh(g);
            ghi[k0][j] = (short)h2;
            glo[k0][j] = (short)f2bh(g - b2f(h2));
        }
    }

    #pragma unroll
    for (int tt = 0; tt < 4; ++tt) {
        f32x4 accQ = (f32x4){0.f, 0.f, 0.f, 0.f};
        f32x4 accG = (f32x4){0.f, 0.f, 0.f, 0.f};
        #pragma unroll
        for (int k0 = 0; k0 < 2; ++k0) {
            short8 bhi, blo;
            const float* sp = &S0l[(16 * tt + lr) * 65 + k0 * 32 + lg * 8];
            #pragma unroll
            for (int j = 0; j < 8; ++j) {
                float s = sp[j];
                unsigned short h = f2bh(s);
                bhi[j] = (short)h;
                blo[j] = (short)f2bh(s - b2f(h));
            }
            accQ = __builtin_amdgcn_mfma_f32_16x16x32_bf16(qhi[k0], bhi, accQ, 0, 0, 0);
            accQ = __builtin_amdgcn_mfma_f32_16x16x32_bf16(qhi[k0], blo, accQ, 0, 0, 0);
            accQ = __builtin_amdgcn_mfma_f32_16x16x32_bf16(qlo[k0], bhi, accQ, 0, 0, 0);
            accG = __builtin_amdgcn_mfma_f32_16x16x32_bf16(ghi[k0], bhi, accG, 0, 0, 0);
            accG = __builtin_amdgcn_mfma_f32_16x16x32_bf16(ghi[k0], blo, accG, 0, 0, 0);
            accG = __builtin_amdgcn_mfma_f32_16x16x32_bf16(glo[k0], bhi, accG, 0, 0, 0);
        }
        #pragma unroll
        for (int r = 0; r < 4; ++r) {
            const size_t off = base0 + (size_t)(16 * w + 4 * lg + r) * Cn + 16 * tt + lr;
            SAp[off] += accQ[r];
            Yp[off]  += accG[r];
        }
    }
}

// ---------- elementwise stage 2: groupnorm + bonus + (x_att*g) -> AG (bf16) ----------
__global__ __launch_bounds__(256) void k_elem2(
    const float* __restrict__ Yb, const unsigned short* __restrict__ Rb,
    const unsigned short* __restrict__ Kb, const unsigned short* __restrict__ Vb,
    const unsigned short* __restrict__ Gb,
    const float* __restrict__ gnw, const float* __restrict__ gnb,
    const float* __restrict__ rk,
    unsigned short* __restrict__ AG)
{
    int tid = threadIdx.x;
    size_t gh = (size_t)blockIdx.x * 4 + (tid >> 6);
    int lane = tid & 63;
    int h = (int)(gh & (Hn - 1));
    size_t idx = (gh >> 4) * Cn + (size_t)h * Nn + lane;
    int c = h * Nn + lane;

    float y = Yb[idx];
    float s1 = y, s2 = y * y;
    float p = b2f(Rb[idx]) * b2f(Kb[idx]) * rk[c];
    #pragma unroll
    for (int m = 1; m < 64; m <<= 1) {
        s1 += __shfl_xor(s1, m, 64);
        s2 += __shfl_xor(s2, m, 64);
        p  += __shfl_xor(p, m, 64);
    }
    float mean = s1 * (1.f / 64.f);
    float var = s2 * (1.f / 64.f) - mean * mean;
    float xn = (y - mean) * rsqrtf(var + 0.00064f) * gnw[c] + gnb[c];
    float xatt = xn + p * b2f(Vb[idx]);
    AG[idx] = f2b(xatt * b2f(Gb[idx]));
}

// ---------- layernorm of sa_out -> state_rep + fused v_first copy ----------
__global__ __launch_bounds__(256) void k_ln(
    const float* __restrict__ SAp,
    const float* __restrict__ lnw, const float* __restrict__ lnb,
    const float* __restrict__ vf_in, float* __restrict__ vf_out,
    float* __restrict__ outp)
{
    __shared__ float red1[4], red2[4];
    int tid = threadIdx.x;
    size_t row = blockIdx.x;
    *(f32x4*)(vf_out + row * Cn + tid * 4) = *(const f32x4*)(vf_in + row * Cn + tid * 4);

    f32x4 v = *(const f32x4*)(SAp + row * Cn + tid * 4);
    float s1 = v[0] + v[1] + v[2] + v[3];
    float s2 = v[0] * v[0] + v[1] * v[1] + v[2] * v[2] + v[3] * v[3];
    #pragma unroll
    for (int m = 1; m < 64; m <<= 1) {
        s1 += __shfl_xor(s1, m, 64);
        s2 += __shfl_xor(s2, m, 64);
    }
    if ((tid & 63) == 0) { red1[tid >> 6] = s1; red2[tid >> 6] = s2; }
    __syncthreads();
    s1 = red1[0] + red1[1] + red1[2] + red1[3];
    s2 = red2[0] + red2[1] + red2[2] + red2[3];
    float mean = s1 * (1.f / 1024.f);
    float var = s2 * (1.f / 1024.f) - mean * mean;
    float rs = rsqrtf(var + 1e-5f);
    f32x4 o;
    #pragma unroll
    for (int u = 0; u < 4; ++u) {
        int c = tid * 4 + u;
        o[u] = (v[u] - mean) * rs * lnw[c] + lnb[c];
    }
    *(f32x4*)(outp + row * Cn + tid * 4) = o;
}

// ---------- launcher ----------
extern "C" void kernel_launch(void* const* d_in, const int* in_sizes, int n_in,
                              void* d_out, int out_size, void* d_ws, size_t ws_size,
                              hipStream_t stream)
{
    (void)in_sizes; (void)n_in; (void)out_size; (void)ws_size;
    const float* x      = (const float*)d_in[0];
    const float* vfirst = (const float*)d_in[1];
    const float* x_r    = (const float*)d_in[2];
    const float* x_w    = (const float*)d_in[3];
    const float* x_k    = (const float*)d_in[4];
    const float* x_v    = (const float*)d_in[5];
    const float* x_a    = (const float*)d_in[6];
    const float* x_g    = (const float*)d_in[7];
    const float* w0     = (const float*)d_in[8];
    const float* w1     = (const float*)d_in[9];
    const float* w2     = (const float*)d_in[10];
    const float* a0     = (const float*)d_in[11];
    const float* a1     = (const float*)d_in[12];
    const float* a2     = (const float*)d_in[13];
    const float* v0     = (const float*)d_in[14];
    const float* v1     = (const float*)d_in[15];
    const float* v2     = (const float*)d_in[16];
    const float* g1     = (const float*)d_in[17];
    const float* g2     = (const float*)d_in[18];
    const float* k_k    = (const float*)d_in[19];
    const float* k_a    = (const float*)d_in[20];
    const float* r_k    = (const float*)d_in[21];
    const float* Wr     = (const float*)d_in[22];
    const float* Wk     = (const float*)d_in[23];
    const float* Wv     = (const float*)d_in[24];
    const float* Wo     = (const float*)d_in[25];
    const float* gn_w   = (const float*)d_in[26];
    const float* gn_b   = (const float*)d_in[27];
    const float* ln_w   = (const float*)d_in[28];
    const float* ln_b   = (const float*)d_in[29];

    char* ws = (char*)d_ws;
    size_t off = 0;
    auto alloc = [&](size_t bytes) -> void* {
        void* p = ws + off;
        off += (bytes + 255) & ~(size_t)255;
        return p;
    };
    // bf16 big buffers (8 MiB each)
    unsigned short* Rb  = (unsigned short*)alloc(MX * 2);  // raw r; reused as AG
    unsigned short* Kb  = (unsigned short*)alloc(MX * 2);  // raw k -> k_final (kA)
    unsigned short* Vb  = (unsigned short*)alloc(MX * 2);  // raw v -> v_final (kA)
    unsigned short* SVb = (unsigned short*)alloc(MX * 2);  // sigmoid(v-gate)
    unsigned short* Ab  = (unsigned short*)alloc(MX * 2);  // sigmoid(a)
    unsigned short* Gb  = (unsigned short*)alloc(MX * 2);  // g
    float* Wdec = (float*)alloc(MX * 4);                   // decay (f32)
    float* Cg   = (float*)alloc(MX * 4);                   // chunk offsets Z
    float* Pg   = (float*)alloc(MX * 4);                   // chunk transfer mats
    float* Qg   = (float*)alloc(MX * 4);                   // q_t vectors
    float* Gg   = (float*)alloc(MX * 4);                   // g_t vectors
    // small intermediates (bf16)
    unsigned short* hw = (unsigned short*)alloc((size_t)Mrows * 64 * 2);
    unsigned short* ha = (unsigned short*)alloc((size_t)Mrows * 64 * 2);
    unsigned short* hv = (unsigned short*)alloc((size_t)Mrows * 64 * 2);
    unsigned short* hg = (unsigned short*)alloc((size_t)Mrows * 160 * 2);
    // bf16 weights
    unsigned short* WrB = (unsigned short*)alloc(1048576 * 2);
    unsigned short* WkB = (unsigned short*)alloc(1048576 * 2);
    unsigned short* WvB = (unsigned short*)alloc(1048576 * 2);
    unsigned short* WoB = (unsigned short*)alloc(1048576 * 2);
    unsigned short* w1T = (unsigned short*)alloc(65536 * 2);
    unsigned short* w2T = (unsigned short*)alloc(65536 * 2);
    unsigned short* a1T = (unsigned short*)alloc(65536 * 2);
    unsigned short* a2T = (unsigned short*)alloc(65536 * 2);
    unsigned short* v1T = (unsigned short*)alloc(65536 * 2);
    unsigned short* v2T = (unsigned short*)alloc(65536 * 2);
    unsigned short* g1T = (unsigned short*)alloc(163840 * 2);
    unsigned short* g2T = (unsigned short*)alloc(163840 * 2);
    // ~140 MiB total

    // premix buffers alias later-written regions (dead before those writes):
    unsigned short* xrB = (unsigned short*)Cg;             // dead before kA writes Cg
    unsigned short* xkB = (unsigned short*)Cg + MX;
    unsigned short* xvB = (unsigned short*)Wdec;           // dead before gemm_s2-Wdec
    unsigned short* xgB = (unsigned short*)Wdec + MX;
    unsigned short* xwB = Ab;                              // dead before gemm_s2-Ab
    unsigned short* xaB = Gb;                              // dead before gemm_s2-Gb

    float* out_o  = (float*)d_out;
    float* out_vf = out_o + MX;
    float* out_sr = out_o + 2 * MX;
    float* Sinit = out_vf;                  // chunk-initial states (dead after kD)
    float* Yb    = out_o;                   // y0 + corrections (consumed by k_elem2)
    float* SAb   = out_sr;                  // sa0 + corrections (LN'd in place)
    unsigned short* AG = Rb;

    // fused prep: premix + weight cvt + transposes (one launch)
    k_prep_all<<<dim3(8960), 256, 0, stream>>>(
        x, x_r, x_w, x_k, x_v, x_a, x_g,
        xrB, xwB, xkB, xvB, xaB, xgB,
        Wr, Wk, Wv, Wo, WrB, WkB, WvB, WoB,
        w1, w2, a1, a2, v1, v2, g1, g2,
        w1T, w2T, a1T, a2T, v1T, v2T, g1T, g2T);

    // stage-1 GEMMs (small first: consumes xw/xa/xv/xg before rkv writes R/K/V)
    gemm_small1<<<dim3(16, 3, 4), 256, 0, stream>>>(xwB, xaB, xvB, xgB,
                                                    w1T, a1T, v1T, g1T,
                                                    hw, ha, hv, hg);
    gemm_rkv<<<dim3(32, 8, 3), 256, 0, stream>>>(xrB, xkB, xvB, WrB, WkB, WvB,
                                                 Rb, Kb, Vb);

    // stage-2 GEMMs in one z-batched launch (compile-time epilogues)
    gemm_s2<<<dim3(32, 8, 4), 256, 0, stream>>>(hw, ha, hv, hg,
                                                w2T, a2T, v2T, g2T,
                                                Wdec, Ab, SVb, Gb,
                                                w0, a0, v0);

    // chunked scan: A2 (fused elem1 + zero-init recurrence), B (combine), D (correct)
    kA_chunk<<<dim3(1024), 512, 0, stream>>>(Wdec, Kb, Vb, SVb, Ab, Rb,
                                             vfirst, k_k, k_a,
                                             Pg, Cg, Qg, Gg, Yb, SAb);
    kB_combine<<<dim3(64), 256, 0, stream>>>(Pg, Cg, Sinit);
    kD_corr<<<dim3(960), 256, 0, stream>>>(Sinit, Qg, Gg, SAb, Yb);

    k_elem2<<<dim3(16384), 256, 0, stream>>>(Yb, Rb, Kb, Vb, Gb, gn_w, gn_b, r_k, AG);

    // real outputs (k_ln also copies v_first; Sinit in out_vf is dead after kD)
    k_ln<<<dim3(4096), 256, 0, stream>>>(SAb, ln_w, ln_b, vfirst, out_vf, out_sr);
    gemm2<0, 1><<<dim3(32, 8), 256, 0, stream>>>(AG, Cn, WoB, Cn, out_o, nullptr, Cn, nullptr, Cn);
}

// Round 12
// 340.943 us; speedup vs baseline: 1.1454x; 1.0445x over previous
//
#include <hip/hip_runtime.h>
#include <hip/hip_bf16.h>
#include <cstdint>
#include <cstddef>

// ---------- types & helpers ----------
typedef __attribute__((ext_vector_type(8))) short short8;   // 8 x bf16
typedef __attribute__((ext_vector_type(4))) short short4v;  // 4 x bf16 (8B)
typedef __attribute__((ext_vector_type(4))) float f32x4;

#define DEVINL static __device__ __forceinline__

DEVINL float b2f(unsigned short u) {
    union { unsigned int i; float f; } v; v.i = ((unsigned int)u) << 16; return v.f;
}
DEVINL unsigned short f2b(float f) {
    union { float f; unsigned int i; } v; v.f = f;
    unsigned int x = v.i;
    return (unsigned short)((x + 0x7FFFu + ((x >> 16) & 1u)) >> 16);
}
// hardware cvt (compiler emits single-instr bf16 convert)
DEVINL unsigned short f2bh(float f) {
    __hip_bfloat16 h = __float2bfloat16(f);
    union { __hip_bfloat16 h; unsigned short u; } v; v.h = h; return v.u;
}
// short8 (8 bf16) -> two f32x4
DEVINL void cv8(short8 h, f32x4& lo, f32x4& hi) {
    #pragma unroll
    for (int j = 0; j < 4; ++j) {
        lo[j] = b2f((unsigned short)h[j]);
        hi[j] = b2f((unsigned short)h[j + 4]);
    }
}
// async global->LDS, 16B per lane; LDS dest is wave-uniform base + lane*16
DEVINL void stage16(const unsigned short* g, unsigned short* l) {
    __builtin_amdgcn_global_load_lds(
        (const __attribute__((address_space(1))) unsigned int*)g,
        (__attribute__((address_space(3))) unsigned int*)l,
        16, 0, 0);
}

static constexpr int Bsz = 4, Tn = 1024, Cn = 1024, Hn = 16, Nn = 64;
static constexpr int Mrows = Bsz * Tn;             // 4096
static constexpr size_t MX = (size_t)Mrows * Cn;   // 4,194,304
static constexpr int NCHUNK = 16, CL = 64;         // 16 chunks x 64 steps

// ---------- fused prep: token-shift premix + big-weight cvt + small transposes ----------
__global__ __launch_bounds__(256) void k_prep_all(
    const float* __restrict__ x,
    const float* __restrict__ mr, const float* __restrict__ mw,
    const float* __restrict__ mk, const float* __restrict__ mv,
    const float* __restrict__ ma, const float* __restrict__ mg,
    unsigned short* __restrict__ xr, unsigned short* __restrict__ xw,
    unsigned short* __restrict__ xk, unsigned short* __restrict__ xv,
    unsigned short* __restrict__ xa, unsigned short* __restrict__ xg,
    const float* __restrict__ Wr, const float* __restrict__ Wk,
    const float* __restrict__ Wv, const float* __restrict__ Wo,
    unsigned short* __restrict__ WrB, unsigned short* __restrict__ WkB,
    unsigned short* __restrict__ WvB, unsigned short* __restrict__ WoB,
    const float* __restrict__ w1, const float* __restrict__ w2,
    const float* __restrict__ a1, const float* __restrict__ a2,
    const float* __restrict__ v1, const float* __restrict__ v2,
    const float* __restrict__ g1, const float* __restrict__ g2,
    unsigned short* __restrict__ w1T, unsigned short* __restrict__ w2T,
    unsigned short* __restrict__ a1T, unsigned short* __restrict__ a2T,
    unsigned short* __restrict__ v1T, unsigned short* __restrict__ v2T,
    unsigned short* __restrict__ g1T, unsigned short* __restrict__ g2T)
{
    const int bx = blockIdx.x;
    const int tid = threadIdx.x;
    if (bx < 2048) {
        size_t e = ((size_t)bx * 256 + tid) * 8;
        int c = (int)(e & (Cn - 1));
        int t = (int)((e >> 10) & (Tn - 1));
        float xf[8], d[8];
        {
            f32x4 x0 = *(const f32x4*)(x + e);
            f32x4 x1 = *(const f32x4*)(x + e + 4);
            #pragma unroll
            for (int j = 0; j < 4; ++j) { xf[j] = x0[j]; xf[4 + j] = x1[j]; }
        }
        if (t > 0) {
            f32x4 p0 = *(const f32x4*)(x + e - Cn);
            f32x4 p1 = *(const f32x4*)(x + e - Cn + 4);
            #pragma unroll
            for (int j = 0; j < 4; ++j) { d[j] = p0[j] - xf[j]; d[4 + j] = p1[j] - xf[4 + j]; }
        } else {
            #pragma unroll
            for (int j = 0; j < 8; ++j) d[j] = -xf[j];
        }
        const float* ms[6] = { mr, mw, mk, mv, ma, mg };
        unsigned short* ds[6] = { xr, xw, xk, xv, xa, xg };
        #pragma unroll
        for (int p = 0; p < 6; ++p) {
            f32x4 m0 = *(const f32x4*)(ms[p] + c);
            f32x4 m1 = *(const f32x4*)(ms[p] + c + 4);
            short8 o;
            #pragma unroll
            for (int j = 0; j < 4; ++j) {
                o[j]     = (short)f2b(xf[j]     + d[j]     * m0[j]);
                o[4 + j] = (short)f2b(xf[4 + j] + d[4 + j] * m1[j]);
            }
            *(short8*)(ds[p] + e) = o;
        }
    } else if (bx < 6144) {
        int b2 = bx - 2048;
        int sel = b2 >> 10;
        const float* in = (sel == 0) ? Wr : (sel == 1) ? Wk : (sel == 2) ? Wv : Wo;
        unsigned short* out = (sel == 0) ? WrB : (sel == 1) ? WkB : (sel == 2) ? WvB : WoB;
        int i = (((b2 & 1023) << 8) + tid) * 4;
        f32x4 v = *(const f32x4*)(in + i);
        short4v o;
        #pragma unroll
        for (int j = 0; j < 4; ++j) o[j] = (short)f2b(v[j]);
        *(short4v*)(out + i) = o;
    } else {
        int idx = (bx - 6144) * 256 + tid;
        if (idx < 65536) {
            int r = idx >> 6, c = idx & 63;
            w1T[c * 1024 + r] = f2b(w1[idx]);
        } else if (idx < 131072) {
            int j = idx - 65536; int r = j >> 10, c = j & 1023;
            w2T[c * 64 + r] = f2b(w2[j]);
        } else if (idx < 196608) {
            int j = idx - 131072; int r = j >> 6, c = j & 63;
            a1T[c * 1024 + r] = f2b(a1[j]);
        } else if (idx < 262144) {
            int j = idx - 196608; int r = j >> 10, c = j & 1023;
            a2T[c * 64 + r] = f2b(a2[j]);
        } else if (idx < 327680) {
            int j = idx - 262144; int r = j >> 6, c = j & 63;
            v1T[c * 1024 + r] = f2b(v1[j]);
        } else if (idx < 393216) {
            int j = idx - 327680; int r = j >> 10, c = j & 1023;
            v2T[c * 64 + r] = f2b(v2[j]);
        } else if (idx < 557056) {
            int j = idx - 393216; int r = j / 160, c = j - r * 160;
            g1T[c * 1024 + r] = f2b(g1[j]);
        } else if (idx < 720896) {
            int j = idx - 557056; int r = j >> 10, c = j & 1023;
            g2T[c * 160 + r] = f2b(g2[j]);
        }
    }
}

// epi: 0=raw 1=tanh 2=sigmoid 3=bias+sigmoid 4=bias+decay
template<int EPI, int OUTF32>
DEVINL void gemm_epi(f32x4 (&acc)[4][4], int m0, int n0, int N, int ldc,
                     float* Cf, unsigned short* Cb, const float* bias, int lane)
{
    int r16 = lane & 15;
    #pragma unroll
    for (int mi = 0; mi < 4; ++mi)
        #pragma unroll
        for (int ni = 0; ni < 4; ++ni) {
            int col = n0 + ni * 16 + r16;
            if (col < N) {
                float bv = (EPI >= 3) ? bias[col] : 0.f;
                #pragma unroll
                for (int r = 0; r < 4; ++r) {
                    int row = m0 + mi * 16 + (lane >> 4) * 4 + r;
                    float v = acc[mi][ni][r];
                    if (EPI == 1) v = tanhf(v);
                    else if (EPI == 2) v = 1.f / (1.f + expf(-v));
                    else if (EPI == 3) { v += bv; v = 1.f / (1.f + expf(-v)); }
                    else if (EPI == 4) { v += bv; v = expf(-0.60653066f / (1.f + expf(-v))); }
                    size_t o = (size_t)row * ldc + col;
                    if (OUTF32) Cf[o] = v; else Cb[o] = f2b(v);
                }
            }
        }
}

// ---------- LDS-staged GEMM body: 128x128 tile, BK=32, double-buffered ----------
template<int EPI, int OUTF32>
DEVINL void gemm_lds_body(const unsigned short* __restrict__ A, int lda,
                          const unsigned short* __restrict__ Bt, int ldb,
                          float* __restrict__ Cf, unsigned short* __restrict__ Cb,
                          int ldc, const float* __restrict__ bias, int K,
                          int m0, int n0)
{
    __shared__ unsigned short As[2][128 * 32];
    __shared__ unsigned short Bs[2][128 * 32];
    const int tid = threadIdx.x, wid = tid >> 6, lane = tid & 63;
    const int r16 = lane & 15, kg = lane >> 4;
    const int wr = (wid >> 1) * 64, wc = (wid & 1) * 64;

    const int srow = wid * 32 + (lane >> 2);
    const int scol = (lane & 3) * 8;
    const int lbase = wid * 1024 + lane * 8;
    const unsigned short* aS = A + (size_t)(m0 + srow) * lda + scol;
    const unsigned short* bS = Bt + (size_t)(n0 + srow) * ldb + scol;

    f32x4 acc[4][4];
    #pragma unroll
    for (int a = 0; a < 4; ++a)
        #pragma unroll
        for (int b = 0; b < 4; ++b) acc[a][b] = (f32x4){0.f, 0.f, 0.f, 0.f};

    const int nk = K >> 5;
    stage16(aS, &As[0][lbase]);
    stage16(aS + (size_t)16 * lda, &As[0][lbase + 512]);
    stage16(bS, &Bs[0][lbase]);
    stage16(bS + (size_t)16 * ldb, &Bs[0][lbase + 512]);
    __syncthreads();

    for (int kk = 0; kk < nk; ++kk) {
        const int buf = kk & 1;
        if (kk + 1 < nk) {
            const int k0 = (kk + 1) * 32;
            stage16(aS + k0, &As[buf ^ 1][lbase]);
            stage16(aS + k0 + (size_t)16 * lda, &As[buf ^ 1][lbase + 512]);
            stage16(bS + k0, &Bs[buf ^ 1][lbase]);
            stage16(bS + k0 + (size_t)16 * ldb, &Bs[buf ^ 1][lbase + 512]);
        }
        short8 af[4], bf[4];
        #pragma unroll
        for (int mi = 0; mi < 4; ++mi)
            af[mi] = *(const short8*)&As[buf][(wr + mi * 16 + r16) * 32 + kg * 8];
        #pragma unroll
        for (int ni = 0; ni < 4; ++ni)
            bf[ni] = *(const short8*)&Bs[buf][(wc + ni * 16 + r16) * 32 + kg * 8];
        #pragma unroll
        for (int mi = 0; mi < 4; ++mi)
            #pragma unroll
            for (int ni = 0; ni < 4; ++ni)
                acc[mi][ni] = __builtin_amdgcn_mfma_f32_16x16x32_bf16(af[mi], bf[ni], acc[mi][ni], 0, 0, 0);
        __syncthreads();
    }
    gemm_epi<EPI, OUTF32>(acc, m0 + wr, n0 + wc, 1 << 30, ldc, Cf, Cb, bias, lane);
}

// ---------- R/K/V GEMMs in one launch ----------
__global__ __launch_bounds__(256) void gemm_rkv(
    const unsigned short* __restrict__ A0, const unsigned short* __restrict__ A1,
    const unsigned short* __restrict__ A2,
    const unsigned short* __restrict__ B0, const unsigned short* __restrict__ B1,
    const unsigned short* __restrict__ B2,
    unsigned short* __restrict__ D0, unsigned short* __restrict__ D1,
    unsigned short* __restrict__ D2)
{
    int z = blockIdx.z;
    const unsigned short* A = (z == 0) ? A0 : (z == 1) ? A1 : A2;
    const unsigned short* Bt = (z == 0) ? B0 : (z == 1) ? B1 : B2;
    unsigned short* D = (z == 0) ? D0 : (z == 1) ? D1 : D2;
    gemm_lds_body<0, 0>(A, Cn, Bt, Cn, nullptr, D, Cn, nullptr, Cn,
                        blockIdx.x * 128, blockIdx.y * 128);
}

// ---------- the four stage-2 GEMMs in ONE launch ----------
__global__ __launch_bounds__(256) void gemm_s2(
    const unsigned short* __restrict__ hw, const unsigned short* __restrict__ ha,
    const unsigned short* __restrict__ hv, const unsigned short* __restrict__ hg,
    const unsigned short* __restrict__ w2T, const unsigned short* __restrict__ a2T,
    const unsigned short* __restrict__ v2T, const unsigned short* __restrict__ g2T,
    float* __restrict__ Wdec, unsigned short* __restrict__ Ab,
    unsigned short* __restrict__ SVb, unsigned short* __restrict__ Gb,
    const float* __restrict__ w0, const float* __restrict__ a0,
    const float* __restrict__ v0)
{
    const int z = blockIdx.z;
    const int m0 = blockIdx.x * 128, n0 = blockIdx.y * 128;
    if (z == 0)
        gemm_lds_body<4, 1>(hw, 64, w2T, 64, Wdec, nullptr, Cn, w0, 64, m0, n0);
    else if (z == 1)
        gemm_lds_body<3, 0>(ha, 64, a2T, 64, nullptr, Ab, Cn, a0, 64, m0, n0);
    else if (z == 2)
        gemm_lds_body<3, 0>(hv, 64, v2T, 64, nullptr, SVb, Cn, v0, 64, m0, n0);
    else
        gemm_lds_body<0, 0>(hg, 160, g2T, 160, nullptr, Gb, Cn, nullptr, 160, m0, n0);
}

// ---------- generic LDS-staged 128x128 GEMM (Wo) ----------
template<int EPI, int OUTF32>
__global__ __launch_bounds__(256) void gemm2(
    const unsigned short* __restrict__ A, int lda,
    const unsigned short* __restrict__ Bt, int ldb,
    float* __restrict__ Cf, unsigned short* __restrict__ Cb, int ldc,
    const float* __restrict__ bias, int K)
{
    gemm_lds_body<EPI, OUTF32>(A, lda, Bt, ldb, Cf, Cb, ldc, bias, K,
                               blockIdx.x * 128, blockIdx.y * 128);
}

// ---------- direct-global MFMA core (tall-skinny stage-1) ----------
DEVINL void gemm_core(const unsigned short* __restrict__ A, int lda,
                      const unsigned short* __restrict__ Bt, int ldb,
                      int m0, int n0, int N, int K, int r16, int k8,
                      f32x4 (&acc)[4][4])
{
    for (int k0 = 0; k0 < K; k0 += 32) {
        short8 af[4], bf[4];
        #pragma unroll
        for (int mi = 0; mi < 4; ++mi)
            af[mi] = *(const short8*)(A + (size_t)(m0 + mi * 16 + r16) * lda + k0 + k8);
        #pragma unroll
        for (int ni = 0; ni < 4; ++ni) {
            int rn = n0 + ni * 16 + r16;
            if (rn >= N) rn = N - 1;
            bf[ni] = *(const short8*)(Bt + (size_t)rn * ldb + k0 + k8);
        }
        #pragma unroll
        for (int mi = 0; mi < 4; ++mi)
            #pragma unroll
            for (int ni = 0; ni < 4; ++ni)
                acc[mi][ni] = __builtin_amdgcn_mfma_f32_16x16x32_bf16(af[mi], bf[ni], acc[mi][ni], 0, 0, 0);
    }
}

// ---------- four tall-skinny stage-1 GEMMs in one launch ----------
__global__ __launch_bounds__(256) void gemm_small1(
    const unsigned short* __restrict__ Aw, const unsigned short* __restrict__ Aa,
    const unsigned short* __restrict__ Av, const unsigned short* __restrict__ Ag,
    const unsigned short* __restrict__ Bw, const unsigned short* __restrict__ Ba,
    const unsigned short* __restrict__ Bv, const unsigned short* __restrict__ Bg,
    unsigned short* __restrict__ Dw, unsigned short* __restrict__ Da,
    unsigned short* __restrict__ Dv, unsigned short* __restrict__ Dg)
{
    int z = blockIdx.z;
    if (z < 3 && blockIdx.y > 0) return;
    const unsigned short* A = (z == 0) ? Aw : (z == 1) ? Aa : (z == 2) ? Av : Ag;
    const unsigned short* Bt = (z == 0) ? Bw : (z == 1) ? Ba : (z == 2) ? Bv : Bg;
    const int N = (z == 3) ? 160 : 64;
    const int tid = threadIdx.x, wid = tid >> 6, lane = tid & 63;
    const int r16 = lane & 15, k8 = (lane >> 4) * 8;
    const int m0 = blockIdx.x * 256 + wid * 64;
    const int n0 = blockIdx.y * 64;
    f32x4 acc[4][4];
    #pragma unroll
    for (int a = 0; a < 4; ++a)
        #pragma unroll
        for (int b = 0; b < 4; ++b) acc[a][b] = (f32x4){0.f, 0.f, 0.f, 0.f};
    gemm_core(A, Cn, Bt, Cn, m0, n0, N, Cn, r16, k8, acc);
    if (z == 0)      gemm_epi<1, 0>(acc, m0, n0, N, 64,  nullptr, Dw, nullptr, lane);
    else if (z == 1) gemm_epi<0, 0>(acc, m0, n0, N, 64,  nullptr, Da, nullptr, lane);
    else if (z == 2) gemm_epi<0, 0>(acc, m0, n0, N, 64,  nullptr, Dv, nullptr, lane);
    else             gemm_epi<2, 0>(acc, m0, n0, N, 160, nullptr, Dg, nullptr, lane);
}

// ================= chunked scan =================
// Phase A2 (512 thr, 32KB LDS), k_elem1 fused into staging. bb is ALSO written
// back to Ab (kY needs it). No r / y / g work here anymore (kY computes Y).
__global__ __launch_bounds__(512) void kA_chunk(
    const float* __restrict__ Wp,
    unsigned short* __restrict__ Kp,        // raw k -> k_final (in place)
    unsigned short* __restrict__ Vp,        // raw v -> v_final (in place)
    const unsigned short* __restrict__ SVp, // sigmoid(v-gate)
    unsigned short* __restrict__ Aap,       // sigmoid(a) -> bb (in place)
    const float* __restrict__ vfirst,
    const float* __restrict__ kkw, const float* __restrict__ kaw,
    float* __restrict__ Pg, float* __restrict__ Cg,
    float* __restrict__ Qg, float* __restrict__ SAp)
{
    __shared__ unsigned short kS[CL][64];
    __shared__ unsigned short vS[CL][64];
    __shared__ unsigned short aS[CL][64];    // aa = -kk
    __shared__ unsigned short bS[CL][64];    // bb = kk*a

    const int tid = threadIdx.x;
    const int bx = blockIdx.x;
    const int bh = bx >> 4, c = bx & 15;
    const size_t base0 = ((size_t)(bh >> 4) * Tn + (size_t)c * CL) * Cn + (size_t)(bh & 15) * Nn;

    {   // ---- fused staging + elementwise-1 ----
        const int t = tid >> 3, seg = (tid & 7) * 8;
        const size_t g = base0 + (size_t)t * Cn + seg;
        const int ch = (bh & 15) * Nn + seg;

        f32x4 kv0, kv1, av0, av1, vv0, vv1, sv0, sv1;
        cv8(*(const short8*)(Kp + g), kv0, kv1);
        cv8(*(const short8*)(Aap + g), av0, av1);
        cv8(*(const short8*)(Vp + g), vv0, vv1);
        cv8(*(const short8*)(SVp + g), sv0, sv1);
        f32x4 kkw0 = *(const f32x4*)(kkw + ch), kkw1 = *(const f32x4*)(kkw + ch + 4);
        f32x4 kaw0 = *(const f32x4*)(kaw + ch), kaw1 = *(const f32x4*)(kaw + ch + 4);
        f32x4 vf0  = *(const f32x4*)(vfirst + g), vf1 = *(const f32x4*)(vfirst + g + 4);

        f32x4 kkv0 = kv0 * kkw0, kkv1 = kv1 * kkw1;
        f32x4 sq = kkv0 * kkv0 + kkv1 * kkv1;
        float s = sq[0] + sq[1] + sq[2] + sq[3];
        s += __shfl_xor(s, 1, 64); s += __shfl_xor(s, 2, 64); s += __shfl_xor(s, 4, 64);
        float inv = 1.f / fmaxf(sqrtf(s), 1e-12f);

        short8 o_a, o_b, o_k, o_v;
        #pragma unroll
        for (int j = 0; j < 4; ++j) {
            float kk_lo = kkv0[j] * inv, kk_hi = kkv1[j] * inv;
            o_a[j]     = (short)f2b(-kk_lo);
            o_a[4 + j] = (short)f2b(-kk_hi);
            o_b[j]     = (short)f2b(kk_lo * av0[j]);
            o_b[4 + j] = (short)f2b(kk_hi * av1[j]);
            float kf_lo = kv0[j] * (1.f + (av0[j] - 1.f) * kaw0[j]);
            float kf_hi = kv1[j] * (1.f + (av1[j] - 1.f) * kaw1[j]);
            o_k[j]     = (short)f2b(kf_lo);
            o_k[4 + j] = (short)f2b(kf_hi);
            float vf_lo = vv0[j] + (vf0[j] - vv0[j]) * sv0[j];
            float vf_hi = vv1[j] + (vf1[j] - vv1[j]) * sv1[j];
            o_v[j]     = (short)f2b(vf_lo);
            o_v[4 + j] = (short)f2b(vf_hi);
        }
        *(short8*)&aS[t][seg] = o_a;
        *(short8*)&bS[t][seg] = o_b;
        *(short8*)&kS[t][seg] = o_k;
        *(short8*)&vS[t][seg] = o_v;
        *(short8*)(Kp + g) = o_k;    // k_final for k_elem2 / kY
        *(short8*)(Vp + g) = o_v;    // v_final for k_elem2 / kY
        *(short8*)(Aap + g) = o_b;   // bb for kY
    }
    __syncthreads();

    const int o = tid & 7, i = tid >> 3;
    f32x4 P0, P1, C0, C1;
    #pragma unroll
    for (int u = 0; u < 4; ++u) {
        P0[u] = (o * 8 + u == i) ? 1.f : 0.f;
        P1[u] = (o * 8 + 4 + u == i) ? 1.f : 0.f;
    }
    C0 = (f32x4){0.f, 0.f, 0.f, 0.f};
    C1 = C0;

    const float* wp = Wp + base0 + o * 8;
    float* sabase = SAp + base0 + i;
    float* qbase = Qg + (size_t)bx * 4096 + i;

    f32x4 w0n = *(const f32x4*)wp;
    f32x4 w1n = *(const f32x4*)(wp + 4);
    #pragma unroll 2
    for (int t = 0; t < CL; ++t) {
        f32x4 w0 = w0n, w1 = w1n;
        if (t + 1 < CL) {
            const size_t nx = (size_t)(t + 1) * Cn;
            w0n = *(const f32x4*)(wp + nx);
            w1n = *(const f32x4*)(wp + nx + 4);
        }

        f32x4 a0, a1;
        cv8(*(const short8*)&aS[t][o * 8], a0, a1);
        f32x4 dp = P0 * a0 + P1 * a1;
        f32x4 dc = C0 * a0 + C1 * a1;
        float pa = dp[0] + dp[1] + dp[2] + dp[3];
        float ca = dc[0] + dc[1] + dc[2] + dc[3];
        pa += __shfl_xor(pa, 1, 64); pa += __shfl_xor(pa, 2, 64); pa += __shfl_xor(pa, 4, 64);
        ca += __shfl_xor(ca, 1, 64); ca += __shfl_xor(ca, 2, 64); ca += __shfl_xor(ca, 4, 64);

        float vi = b2f(vS[t][i]);
        f32x4 k0, k1, b0, b1;
        cv8(*(const short8*)&kS[t][o * 8], k0, k1);
        cv8(*(const short8*)&bS[t][o * 8], b0, b1);

        C0 = C0 * w0 + b0 * ca + k0 * vi;
        C1 = C1 * w1 + b1 * ca + k1 * vi;
        P0 = P0 * w0 + b0 * pa;
        P1 = P1 * w1 + b1 * pa;

        if (o == 0) {
            sabase[(size_t)t * Cn] = ca;
            qbase[t * 64] = pa;
        }
    }

    const size_t ob = (size_t)bx * 4096 + (size_t)i * 64 + o * 8;
    *(f32x4*)(Pg + ob)     = P0;
    *(f32x4*)(Pg + ob + 4) = P1;
    *(f32x4*)(Cg + ob)     = C0;
    *(f32x4*)(Cg + ob + 4) = C1;
}

// Phase B (MFMA): sequential chunk combine S <- S*P_c + C_c via matrix pipe.
__global__ __launch_bounds__(256, 1) void kB_combine(
    const float* __restrict__ Pg, const float* __restrict__ Cg,
    float* __restrict__ Sinit)
{
    __shared__ float Sl[64 * 65];
    __shared__ float PT[64 * 65];
    const int tid = threadIdx.x;
    const int w = tid >> 6;
    const int l = tid & 63;
    const int lr = l & 15;
    const int lg = l >> 4;
    const int bh = blockIdx.x;

    f32x4 acc[4];
    #pragma unroll
    for (int t = 0; t < 4; ++t) acc[t] = (f32x4){0.f, 0.f, 0.f, 0.f};

    f32x4 pr[4]; f32x4 cr[4];
    {
        const size_t ob = (size_t)(bh * 16) * 4096;
        #pragma unroll
        for (int u = 0; u < 4; ++u)
            pr[u] = *(const f32x4*)(Pg + ob + (size_t)tid * 16 + u * 4);
        #pragma unroll
        for (int t = 0; t < 4; ++t)
            #pragma unroll
            for (int r = 0; r < 4; ++r)
                cr[t][r] = Cg[ob + (size_t)(16 * w + 4 * lg + r) * 64 + 16 * t + lr];
    }

    for (int c = 0; c < NCHUNK; ++c) {
        const size_t ob = (size_t)(bh * 16 + c) * 4096;
        #pragma unroll
        for (int t = 0; t < 4; ++t)
            #pragma unroll
            for (int r = 0; r < 4; ++r)
                Sinit[ob + (size_t)(16 * w + 4 * lg + r) * 64 + 16 * t + lr] = acc[t][r];
        if (c == NCHUNK - 1) break;

        #pragma unroll
        for (int t = 0; t < 4; ++t)
            #pragma unroll
            for (int r = 0; r < 4; ++r)
                Sl[(16 * w + 4 * lg + r) * 65 + 16 * t + lr] = acc[t][r];
        {
            const int m = tid >> 2, j0 = (tid & 3) * 16;
            #pragma unroll
            for (int u = 0; u < 4; ++u)
                #pragma unroll
                for (int e = 0; e < 4; ++e)
                    PT[(j0 + u * 4 + e) * 65 + m] = pr[u][e];
        }
        __syncthreads();

        f32x4 prn[4] = {}, crn[4] = {};
        if (c + 1 < NCHUNK - 1) {
            const size_t obn = (size_t)(bh * 16 + c + 1) * 4096;
            #pragma unroll
            for (int u = 0; u < 4; ++u)
                prn[u] = *(const f32x4*)(Pg + obn + (size_t)tid * 16 + u * 4);
            #pragma unroll
            for (int t = 0; t < 4; ++t)
                #pragma unroll
                for (int r = 0; r < 4; ++r)
                    crn[t][r] = Cg[obn + (size_t)(16 * w + 4 * lg + r) * 64 + 16 * t + lr];
        }

        short8 ahi[2], alo[2];
        #pragma unroll
        for (int k0 = 0; k0 < 2; ++k0) {
            const float* sp = &Sl[(16 * w + lr) * 65 + k0 * 32 + lg * 8];
            #pragma unroll
            for (int j = 0; j < 8; ++j) {
                float s = sp[j];
                unsigned short h = f2bh(s);
                ahi[k0][j] = (short)h;
                alo[k0][j] = (short)f2bh(s - b2f(h));
            }
        }

        #pragma unroll
        for (int t = 0; t < 4; ++t) {
            f32x4 nacc = cr[t];
            #pragma unroll
            for (int k0 = 0; k0 < 2; ++k0) {
                short8 bhi, blo;
                const float* pp = &PT[(16 * t + lr) * 65 + k0 * 32 + lg * 8];
                #pragma unroll
                for (int j = 0; j < 8; ++j) {
                    float p = pp[j];
                    unsigned short h = f2bh(p);
                    bhi[j] = (short)h;
                    blo[j] = (short)f2bh(p - b2f(h));
                }
                nacc = __builtin_amdgcn_mfma_f32_16x16x32_bf16(ahi[k0], bhi, nacc, 0, 0, 0);
                nacc = __builtin_amdgcn_mfma_f32_16x16x32_bf16(ahi[k0], blo, nacc, 0, 0, 0);
                nacc = __builtin_amdgcn_mfma_f32_16x16x32_bf16(alo[k0], bhi, nacc, 0, 0, 0);
            }
            acc[t] = nacc;
        }
        __syncthreads();
        #pragma unroll
        for (int u = 0; u < 4; ++u) { pr[u] = prn[u]; cr[u] = crn[u]; }
    }
}

// Phase D (MFMA): SA correction per (chain, chunk>=1):
//   SA_chunk[t][i] += sum_l Q[t][l] * S0[i][l]
__global__ __launch_bounds__(256) void kD_corr(
    const float* __restrict__ Sinit, const float* __restrict__ Qg,
    float* __restrict__ SAp)
{
    __shared__ float Ql[64 * 65];
    __shared__ float S0l[64 * 65];
    const int tid = threadIdx.x;
    const int bx = blockIdx.x;          // 0..959
    const int bh = bx / 15;
    const int c  = 1 + bx % 15;
    const size_t mb = (size_t)(bh * 16 + c) * 4096;
    const size_t base0 = ((size_t)(bh >> 4) * Tn + (size_t)c * CL) * Cn + (size_t)(bh & 15) * Nn;

    {
        const int r = tid >> 2, c4 = (tid & 3) * 16;
        #pragma unroll
        for (int u = 0; u < 4; ++u) {
            *(f32x4*)&Ql[r * 65 + c4 + u * 4]  = *(const f32x4*)(Qg + mb + (size_t)r * 64 + c4 + u * 4);
            *(f32x4*)&S0l[r * 65 + c4 + u * 4] = *(const f32x4*)(Sinit + mb + (size_t)r * 64 + c4 + u * 4);
        }
    }
    __syncthreads();

    const int w = tid >> 6, l = tid & 63, lr = l & 15, lg = l >> 4;

    short8 qhi[2], qlo[2];
    #pragma unroll
    for (int k0 = 0; k0 < 2; ++k0) {
        const float* qp = &Ql[(16 * w + lr) * 65 + k0 * 32 + lg * 8];
        #pragma unroll
        for (int j = 0; j < 8; ++j) {
            float q = qp[j];
            unsigned short h = f2bh(q);
            qhi[k0][j] = (short)h;
            qlo[k0][j] = (short)f2bh(q - b2f(h));
        }
    }

    #pragma unroll
    for (int tt = 0; tt < 4; ++tt) {
        f32x4 accQ = (f32x4){0.f, 0.f, 0.f, 0.f};
        #pragma unroll
        for (int k0 = 0; k0 < 2; ++k0) {
            short8 bhi, blo;
            const float* sp = &S0l[(16 * tt + lr) * 65 + k0 * 32 + lg * 8];
            #pragma unroll
            for (int j = 0; j < 8; ++j) {
                float s = sp[j];
                unsigned short h = f2bh(s);
                bhi[j] = (short)h;
                blo[j] = (short)f2bh(s - b2f(h));
            }
            accQ = __builtin_amdgcn_mfma_f32_16x16x32_bf16(qhi[k0], bhi, accQ, 0, 0, 0);
            accQ = __builtin_amdgcn_mfma_f32_16x16x32_bf16(qhi[k0], blo, accQ, 0, 0, 0);
            accQ = __builtin_amdgcn_mfma_f32_16x16x32_bf16(qlo[k0], bhi, accQ, 0, 0, 0);
        }
        #pragma unroll
        for (int r = 0; r < 4; ++r) {
            const size_t off = base0 + (size_t)(16 * w + 4 * lg + r) * Cn + 16 * tt + lr;
            SAp[off] += accQ[r];
        }
    }
}

// Phase Y (MFMA, WY-form): per (chain, chunk) compute full Y from corrected SA:
//   Y = Rhat @ S0^T + tril(Rhat Khat^T) @ V + tril(Rhat Bhat^T) @ SA
// with Rhat[t][j] = D_t[j] r_t[j], Khat[s][j] = k_s[j]/D_s[j], Bhat = b_s/D_s,
// D_t[j] = prod_{s<=t} w_s[j]. Masks are lower-INCLUSIVE (s <= t).
__global__ __launch_bounds__(256) void kY_mfma(
    const float* __restrict__ Wp, const unsigned short* __restrict__ Rp,
    const unsigned short* __restrict__ Kp, const unsigned short* __restrict__ Bbp,
    const unsigned short* __restrict__ Vp,
    const float* __restrict__ SAp, const float* __restrict__ Sinit,
    float* __restrict__ Yp)
{
    __shared__ float Dl[64 * 64];                       // cumulative decay; later score scratch
    __shared__ unsigned short khS[64 * 72], klS[64 * 72];
    __shared__ unsigned short bhS[64 * 72], blS[64 * 72];
    __shared__ unsigned short vtS[64 * 72];             // V^T [i][s]; segP overlay in scan
    __shared__ unsigned short sahS[64 * 72], salS[64 * 72];

    unsigned short* scoreS = (unsigned short*)Dl;       // [t*72+s] bf16 (after D dead)
    float* segP = (float*)vtS;                          // [seg*64+j] during scan

    const int tid = threadIdx.x;
    const int bx = blockIdx.x;
    const int bh = bx >> 4, cc = bx & 15;
    const size_t base0 = ((size_t)(bh >> 4) * Tn + (size_t)cc * CL) * Cn + (size_t)(bh & 15) * Nn;
    const size_t mb = (size_t)bx * 4096;

    // ---- 1. cumulative decay scan ----
    float wv[16];
    {
        const int j = tid & 63, seg = tid >> 6;
        float run = 1.f;
        #pragma unroll
        for (int u = 0; u < 16; ++u) {
            wv[u] = Wp[base0 + (size_t)(seg * 16 + u) * Cn + j];
            run *= wv[u];
        }
        segP[seg * 64 + j] = run;
    }
    __syncthreads();
    {
        const int j = tid & 63, seg = tid >> 6;
        float d = 1.f;
        for (int q = 0; q < seg; ++q) d *= segP[q * 64 + j];
        #pragma unroll
        for (int u = 0; u < 16; ++u) {
            d *= wv[u];
            Dl[(seg * 16 + u) * 64 + j] = d;
        }
    }
    __syncthreads();

    const int w = tid >> 6, lane = tid & 63;
    const int r16 = lane & 15, kg = lane >> 4;

    // ---- 2a. per-lane Rhat A-fragments (rows t = 16w + r16), hi/lo ----
    short8 rh[2], rl[2];
    {
        const int t = 16 * w + r16;
        #pragma unroll
        for (int ks = 0; ks < 2; ++ks) {
            const int j0 = ks * 32 + kg * 8;
            short8 rr = *(const short8*)(Rp + base0 + (size_t)t * Cn + j0);
            const float* dp = &Dl[t * 64 + j0];
            #pragma unroll
            for (int jj = 0; jj < 8; ++jj) {
                float rv = b2f((unsigned short)rr[jj]) * dp[jj];
                unsigned short h = f2bh(rv);
                rh[ks][jj] = (short)h;
                rl[ks][jj] = (short)f2bh(rv - b2f(h));
            }
        }
    }

    // ---- 2b. Khat/Bhat rows + 2c. transpose-stage V^T and SA^T ----
    {
        const int s = tid >> 2, j0 = (tid & 3) * 16;
        const size_t g = base0 + (size_t)s * Cn + j0;
        #pragma unroll
        for (int half = 0; half < 2; ++half) {
            short8 kk8 = *(const short8*)(Kp + g + half * 8);
            short8 bb8 = *(const short8*)(Bbp + g + half * 8);
            short8 okh, okl, obh, obl;
            #pragma unroll
            for (int jj = 0; jj < 8; ++jj) {
                float dd = Dl[s * 64 + j0 + half * 8 + jj];
                float inv = __builtin_amdgcn_rcpf(dd);
                float kv = b2f((unsigned short)kk8[jj]) * inv;
                float bv = b2f((unsigned short)bb8[jj]) * inv;
                unsigned short h1 = f2bh(kv);
                okh[jj] = (short)h1; okl[jj] = (short)f2bh(kv - b2f(h1));
                unsigned short h2 = f2bh(bv);
                obh[jj] = (short)h2; obl[jj] = (short)f2bh(bv - b2f(h2));
            }
            *(short8*)&khS[s * 72 + j0 + half * 8] = okh;
            *(short8*)&klS[s * 72 + j0 + half * 8] = okl;
            *(short8*)&bhS[s * 72 + j0 + half * 8] = obh;
            *(short8*)&blS[s * 72 + j0 + half * 8] = obl;
        }
        const int i0 = (tid & 3) * 16;
        short8 v8a = *(const short8*)(Vp + base0 + (size_t)s * Cn + i0);
        short8 v8b = *(const short8*)(Vp + base0 + (size_t)s * Cn + i0 + 8);
        #pragma unroll
        for (int jj = 0; jj < 8; ++jj) {
            vtS[(i0 + jj) * 72 + s] = (unsigned short)v8a[jj];
            vtS[(i0 + 8 + jj) * 72 + s] = (unsigned short)v8b[jj];
        }
        #pragma unroll
        for (int u = 0; u < 4; ++u) {
            f32x4 sa4 = *(const f32x4*)(SAp + base0 + (size_t)s * Cn + i0 + u * 4);
            #pragma unroll
            for (int e = 0; e < 4; ++e) {
                unsigned short h = f2bh(sa4[e]);
                sahS[(i0 + u * 4 + e) * 72 + s] = h;
                salS[(i0 + u * 4 + e) * 72 + s] = f2bh(sa4[e] - b2f(h));
            }
        }
    }
    __syncthreads();   // D consumed; score region may now be overwritten

    // ---- 3. matmuls ----
    f32x4 acc[4];
    #pragma unroll
    for (int ni = 0; ni < 4; ++ni) acc[ni] = (f32x4){0.f, 0.f, 0.f, 0.f};

    // Y1 = Rhat @ S0^T  (B-frags read from global, hi/lo)
    #pragma unroll
    for (int ni = 0; ni < 4; ++ni) {
        #pragma unroll
        for (int ks = 0; ks < 2; ++ks) {
            const int i = ni * 16 + r16;
            const int j0 = ks * 32 + kg * 8;
            f32x4 s0a = *(const f32x4*)(Sinit + mb + (size_t)i * 64 + j0);
            f32x4 s0b = *(const f32x4*)(Sinit + mb + (size_t)i * 64 + j0 + 4);
            short8 s0h, s0l;
            #pragma unroll
            for (int jj = 0; jj < 4; ++jj) {
                unsigned short h1 = f2bh(s0a[jj]);
                s0h[jj] = (short)h1; s0l[jj] = (short)f2bh(s0a[jj] - b2f(h1));
                unsigned short h2 = f2bh(s0b[jj]);
                s0h[4 + jj] = (short)h2; s0l[4 + jj] = (short)f2bh(s0b[jj] - b2f(h2));
            }
            acc[ni] = __builtin_amdgcn_mfma_f32_16x16x32_bf16(rh[ks], s0h, acc[ni], 0, 0, 0);
            acc[ni] = __builtin_amdgcn_mfma_f32_16x16x32_bf16(rh[ks], s0l, acc[ni], 0, 0, 0);
            acc[ni] = __builtin_amdgcn_mfma_f32_16x16x32_bf16(rl[ks], s0h, acc[ni], 0, 0, 0);
        }
    }

    // Kr = Rhat @ Khat^T, mask s<=t, store bf16 (wave-local rows)
    #pragma unroll
    for (int si = 0; si < 4; ++si) {
        f32x4 sc = (f32x4){0.f, 0.f, 0.f, 0.f};
        #pragma unroll
        for (int ks = 0; ks < 2; ++ks) {
            const int srow = si * 16 + r16;
            const int j0 = ks * 32 + kg * 8;
            short8 kbh = *(const short8*)&khS[srow * 72 + j0];
            short8 kbl = *(const short8*)&klS[srow * 72 + j0];
            sc = __builtin_amdgcn_mfma_f32_16x16x32_bf16(rh[ks], kbh, sc, 0, 0, 0);
            sc = __builtin_amdgcn_mfma_f32_16x16x32_bf16(rh[ks], kbl, sc, 0, 0, 0);
            sc = __builtin_amdgcn_mfma_f32_16x16x32_bf16(rl[ks], kbh, sc, 0, 0, 0);
        }
        const int s = si * 16 + r16;
        #pragma unroll
        for (int r = 0; r < 4; ++r) {
            const int t = 16 * w + kg * 4 + r;
            scoreS[t * 72 + s] = (s <= t) ? f2bh(sc[r]) : (unsigned short)0;
        }
    }
    // Y2 += Kr @ V^T
    #pragma unroll
    for (int ni = 0; ni < 4; ++ni) {
        #pragma unroll
        for (int ks = 0; ks < 2; ++ks) {
            short8 af = *(const short8*)&scoreS[(16 * w + r16) * 72 + ks * 32 + kg * 8];
            short8 vf = *(const short8*)&vtS[(ni * 16 + r16) * 72 + ks * 32 + kg * 8];
            acc[ni] = __builtin_amdgcn_mfma_f32_16x16x32_bf16(af, vf, acc[ni], 0, 0, 0);
        }
    }
    __syncthreads();

    // Mr = Rhat @ Bhat^T, mask s<=t
    #pragma unroll
    for (int si = 0; si < 4; ++si) {
        f32x4 sc = (f32x4){0.f, 0.f, 0.f, 0.f};
        #pragma unroll
        for (int ks = 0; ks < 2; ++ks) {
            const int srow = si * 16 + r16;
            const int j0 = ks * 32 + kg * 8;
            short8 bbh = *(const short8*)&bhS[srow * 72 + j0];
            short8 bbl = *(const short8*)&blS[srow * 72 + j0];
            sc = __builtin_amdgcn_mfma_f32_16x16x32_bf16(rh[ks], bbh, sc, 0, 0, 0);
            sc = __builtin_amdgcn_mfma_f32_16x16x32_bf16(rh[ks], bbl, sc, 0, 0, 0);
            sc = __builtin_amdgcn_mfma_f32_16x16x32_bf16(rl[ks], bbh, sc, 0, 0, 0);
        }
        const int s = si * 16 + r16;
        #pragma unroll
        for (int r = 0; r < 4; ++r) {
            const int t = 16 * w + kg * 4 + r;
            scoreS[t * 72 + s] = (s <= t) ? f2bh(sc[r]) : (unsigned short)0;
        }
    }
    // Y3 += Mr @ SA^T (hi/lo)
    #pragma unroll
    for (int ni = 0; ni < 4; ++ni) {
        #pragma unroll
        for (int ks = 0; ks < 2; ++ks) {
            short8 af = *(const short8*)&scoreS[(16 * w + r16) * 72 + ks * 32 + kg * 8];
            short8 sh = *(const short8*)&sahS[(ni * 16 + r16) * 72 + ks * 32 + kg * 8];
            short8 sl = *(const short8*)&salS[(ni * 16 + r16) * 72 + ks * 32 + kg * 8];
            acc[ni] = __builtin_amdgcn_mfma_f32_16x16x32_bf16(af, sh, acc[ni], 0, 0, 0);
            acc[ni] = __builtin_amdgcn_mfma_f32_16x16x32_bf16(af, sl, acc[ni], 0, 0, 0);
        }
    }

    // ---- 4. store Y ----
    #pragma unroll
    for (int ni = 0; ni < 4; ++ni) {
        #pragma unroll
        for (int r = 0; r < 4; ++r) {
            const int t = 16 * w + kg * 4 + r;
            Yp[base0 + (size_t)t * Cn + ni * 16 + r16] = acc[ni][r];
        }
    }
}

// ---------- elementwise stage 2: groupnorm + bonus + (x_att*g) -> AG (bf16) ----------
__global__ __launch_bounds__(256) void k_elem2(
    const float* __restrict__ Yb, const unsigned short* __restrict__ Rb,
    const unsigned short* __restrict__ Kb, const unsigned short* __restrict__ Vb,
    const unsigned short* __restrict__ Gb,
    const float* __restrict__ gnw, const float* __restrict__ gnb,
    const float* __restrict__ rk,
    unsigned short* __restrict__ AG)
{
    int tid = threadIdx.x;
    size_t gh = (size_t)blockIdx.x * 4 + (tid >> 6);
    int lane = tid & 63;
    int h = (int)(gh & (Hn - 1));
    size_t idx = (gh >> 4) * Cn + (size_t)h * Nn + lane;
    int c = h * Nn + lane;

    float y = Yb[idx];
    float s1 = y, s2 = y * y;
    float p = b2f(Rb[idx]) * b2f(Kb[idx]) * rk[c];
    #pragma unroll
    for (int m = 1; m < 64; m <<= 1) {
        s1 += __shfl_xor(s1, m, 64);
        s2 += __shfl_xor(s2, m, 64);
        p  += __shfl_xor(p, m, 64);
    }
    float mean = s1 * (1.f / 64.f);
    float var = s2 * (1.f / 64.f) - mean * mean;
    float xn = (y - mean) * rsqrtf(var + 0.00064f) * gnw[c] + gnb[c];
    float xatt = xn + p * b2f(Vb[idx]);
    AG[idx] = f2b(xatt * b2f(Gb[idx]));
}

// ---------- layernorm of sa_out -> state_rep + fused v_first copy ----------
__global__ __launch_bounds__(256) void k_ln(
    const float* __restrict__ SAp,
    const float* __restrict__ lnw, const float* __restrict__ lnb,
    const float* __restrict__ vf_in, float* __restrict__ vf_out,
    float* __restrict__ outp)
{
    __shared__ float red1[4], red2[4];
    int tid = threadIdx.x;
    size_t row = blockIdx.x;
    *(f32x4*)(vf_out + row * Cn + tid * 4) = *(const f32x4*)(vf_in + row * Cn + tid * 4);

    f32x4 v = *(const f32x4*)(SAp + row * Cn + tid * 4);
    float s1 = v[0] + v[1] + v[2] + v[3];
    float s2 = v[0] * v[0] + v[1] * v[1] + v[2] * v[2] + v[3] * v[3];
    #pragma unroll
    for (int m = 1; m < 64; m <<= 1) {
        s1 += __shfl_xor(s1, m, 64);
        s2 += __shfl_xor(s2, m, 64);
    }
    if ((tid & 63) == 0) { red1[tid >> 6] = s1; red2[tid >> 6] = s2; }
    __syncthreads();
    s1 = red1[0] + red1[1] + red1[2] + red1[3];
    s2 = red2[0] + red2[1] + red2[2] + red2[3];
    float mean = s1 * (1.f / 1024.f);
    float var = s2 * (1.f / 1024.f) - mean * mean;
    float rs = rsqrtf(var + 1e-5f);
    f32x4 o;
    #pragma unroll
    for (int u = 0; u < 4; ++u) {
        int c = tid * 4 + u;
        o[u] = (v[u] - mean) * rs * lnw[c] + lnb[c];
    }
    *(f32x4*)(outp + row * Cn + tid * 4) = o;
}

// ---------- launcher ----------
extern "C" void kernel_launch(void* const* d_in, const int* in_sizes, int n_in,
                              void* d_out, int out_size, void* d_ws, size_t ws_size,
                              hipStream_t stream)
{
    (void)in_sizes; (void)n_in; (void)out_size; (void)ws_size;
    const float* x      = (const float*)d_in[0];
    const float* vfirst = (const float*)d_in[1];
    const float* x_r    = (const float*)d_in[2];
    const float* x_w    = (const float*)d_in[3];
    const float* x_k    = (const float*)d_in[4];
    const float* x_v    = (const float*)d_in[5];
    const float* x_a    = (const float*)d_in[6];
    const float* x_g    = (const float*)d_in[7];
    const float* w0     = (const float*)d_in[8];
    const float* w1     = (const float*)d_in[9];
    const float* w2     = (const float*)d_in[10];
    const float* a0     = (const float*)d_in[11];
    const float* a1     = (const float*)d_in[12];
    const float* a2     = (const float*)d_in[13];
    const float* v0     = (const float*)d_in[14];
    const float* v1     = (const float*)d_in[15];
    const float* v2     = (const float*)d_in[16];
    const float* g1     = (const float*)d_in[17];
    const float* g2     = (const float*)d_in[18];
    const float* k_k    = (const float*)d_in[19];
    const float* k_a    = (const float*)d_in[20];
    const float* r_k    = (const float*)d_in[21];
    const float* Wr     = (const float*)d_in[22];
    const float* Wk     = (const float*)d_in[23];
    const float* Wv     = (const float*)d_in[24];
    const float* Wo     = (const float*)d_in[25];
    const float* gn_w   = (const float*)d_in[26];
    const float* gn_b   = (const float*)d_in[27];
    const float* ln_w   = (const float*)d_in[28];
    const float* ln_b   = (const float*)d_in[29];

    char* ws = (char*)d_ws;
    size_t off = 0;
    auto alloc = [&](size_t bytes) -> void* {
        void* p = ws + off;
        off += (bytes + 255) & ~(size_t)255;
        return p;
    };
    unsigned short* Rb  = (unsigned short*)alloc(MX * 2);  // raw r; reused as AG
    unsigned short* Kb  = (unsigned short*)alloc(MX * 2);  // raw k -> k_final (kA)
    unsigned short* Vb  = (unsigned short*)alloc(MX * 2);  // raw v -> v_final (kA)
    unsigned short* SVb = (unsigned short*)alloc(MX * 2);  // sigmoid(v-gate)
    unsigned short* Ab  = (unsigned short*)alloc(MX * 2);  // sigmoid(a) -> bb (kA)
    unsigned short* Gb  = (unsigned short*)alloc(MX * 2);  // g
    float* Wdec = (float*)alloc(MX * 4);                   // decay (f32)
    float* Cg   = (float*)alloc(MX * 4);                   // chunk offsets Z
    float* Pg   = (float*)alloc(MX * 4);                   // chunk transfer mats
    float* Qg   = (float*)alloc(MX * 4);                   // q_t vectors
    unsigned short* hw = (unsigned short*)alloc((size_t)Mrows * 64 * 2);
    unsigned short* ha = (unsigned short*)alloc((size_t)Mrows * 64 * 2);
    unsigned short* hv = (unsigned short*)alloc((size_t)Mrows * 64 * 2);
    unsigned short* hg = (unsigned short*)alloc((size_t)Mrows * 160 * 2);
    unsigned short* WrB = (unsigned short*)alloc(1048576 * 2);
    unsigned short* WkB = (unsigned short*)alloc(1048576 * 2);
    unsigned short* WvB = (unsigned short*)alloc(1048576 * 2);
    unsigned short* WoB = (unsigned short*)alloc(1048576 * 2);
    unsigned short* w1T = (unsigned short*)alloc(65536 * 2);
    unsigned short* w2T = (unsigned short*)alloc(65536 * 2);
    unsigned short* a1T = (unsigned short*)alloc(65536 * 2);
    unsigned short* a2T = (unsigned short*)alloc(65536 * 2);
    unsigned short* v1T = (unsigned short*)alloc(65536 * 2);
    unsigned short* v2T = (unsigned short*)alloc(65536 * 2);
    unsigned short* g1T = (unsigned short*)alloc(163840 * 2);
    unsigned short* g2T = (unsigned short*)alloc(163840 * 2);

    // premix buffers alias later-written regions (dead before those writes):
    unsigned short* xrB = (unsigned short*)Cg;
    unsigned short* xkB = (unsigned short*)Cg + MX;
    unsigned short* xvB = (unsigned short*)Wdec;
    unsigned short* xgB = (unsigned short*)Wdec + MX;
    unsigned short* xwB = Ab;
    unsigned short* xaB = Gb;

    float* out_o  = (float*)d_out;
    float* out_vf = out_o + MX;
    float* out_sr = out_o + 2 * MX;
    float* Sinit = out_vf;                  // chunk-initial states (dead after kY)
    float* Yb    = out_o;                   // Y (written by kY, consumed by k_elem2)
    float* SAb   = out_sr;                  // sa0 + corrections (LN'd in place)
    unsigned short* AG = Rb;

    k_prep_all<<<dim3(8960), 256, 0, stream>>>(
        x, x_r, x_w, x_k, x_v, x_a, x_g,
        xrB, xwB, xkB, xvB, xaB, xgB,
        Wr, Wk, Wv, Wo, WrB, WkB, WvB, WoB,
        w1, w2, a1, a2, v1, v2, g1, g2,
        w1T, w2T, a1T, a2T, v1T, v2T, g1T, g2T);

    gemm_small1<<<dim3(16, 3, 4), 256, 0, stream>>>(xwB, xaB, xvB, xgB,
                                                    w1T, a1T, v1T, g1T,
                                                    hw, ha, hv, hg);
    gemm_rkv<<<dim3(32, 8, 3), 256, 0, stream>>>(xrB, xkB, xvB, WrB, WkB, WvB,
                                                 Rb, Kb, Vb);

    gemm_s2<<<dim3(32, 8, 4), 256, 0, stream>>>(hw, ha, hv, hg,
                                                w2T, a2T, v2T, g2T,
                                                Wdec, Ab, SVb, Gb,
                                                w0, a0, v0);

    // chunked scan: A2 (fused elem1; sa0 + q + P/C), B (combine), D (SA corr), Y (MFMA)
    kA_chunk<<<dim3(1024), 512, 0, stream>>>(Wdec, Kb, Vb, SVb, Ab,
                                             vfirst, k_k, k_a,
                                             Pg, Cg, Qg, SAb);
    kB_combine<<<dim3(64), 256, 0, stream>>>(Pg, Cg, Sinit);
    kD_corr<<<dim3(960), 256, 0, stream>>>(Sinit, Qg, SAb);
    kY_mfma<<<dim3(1024), 256, 0, stream>>>(Wdec, Rb, Kb, Ab, Vb, SAb, Sinit, Yb);

    k_elem2<<<dim3(16384), 256, 0, stream>>>(Yb, Rb, Kb, Vb, Gb, gn_w, gn_b, r_k, AG);

    k_ln<<<dim3(4096), 256, 0, stream>>>(SAb, ln_w, ln_b, vfirst, out_vf, out_sr);
    gemm2<0, 1><<<dim3(32, 8), 256, 0, stream>>>(AG, Cn, WoB, Cn, out_o, nullptr, Cn, nullptr, Cn);
}